// Round 14
// baseline (1512.998 us; speedup 1.0000x reference)
//
#include <hip/hip_runtime.h>
#include <hip/hip_bf16.h>
#include <math.h>

#define B_ 16
#define S_ 512
#define E_ 300
#define H_ 512
#define V_ 10000
#define BS_ (B_ * S_)  // 8192

#define NSL 16           // slices (blocks) per batch, j-split
#define JPB (H_ / NSL)   // 32 output rows per block
#define NBLK (B_ * NSL)  // 256 blocks in the scan

typedef __attribute__((ext_vector_type(4))) float f32x4;
typedef __attribute__((ext_vector_type(8))) short bf16x8;
typedef unsigned long long u64;

// part region: fast[2][B][H] | safe[2][B][H]
#define PART_WORDS (4 * B_ * H_)

// ---------------------------------------------------------------------------
// K0: invalidate exchange tags in BOTH mailboxes.
// ---------------------------------------------------------------------------
__global__ __launch_bounds__(256) void k0_init(u64* __restrict__ part) {
  const int idx = blockIdx.x * 256 + threadIdx.x;
  part[idx] = 0xFFFFFFFF00000000ull;
}

// ---------------------------------------------------------------------------
// K1: xw[bs,h] = sum_e x[bs,e] * W_ih[h,e] + b_ih[h] + b_hh[h]
// ---------------------------------------------------------------------------
__global__ __launch_bounds__(256) void k1_xw(const float* __restrict__ x,
                                             const float* __restrict__ W_ih,
                                             const float* __restrict__ b_ih,
                                             const float* __restrict__ b_hh,
                                             float* __restrict__ xw) {
  __shared__ float As[16][301];
  __shared__ float Ws[16][301];
  const int row0 = blockIdx.x * 16;
  const int col0 = blockIdx.y * 16;
  const int tid = threadIdx.x;
  for (int idx = tid; idx < 16 * E_; idx += 256) {
    int r = idx / E_, c = idx - r * E_;
    As[r][c] = x[(size_t)(row0 + r) * E_ + c];
    Ws[r][c] = W_ih[(size_t)(col0 + r) * E_ + c];
  }
  __syncthreads();
  const int i = tid >> 4, j = tid & 15;
  float acc = 0.f;
#pragma unroll 4
  for (int e = 0; e < E_; ++e) acc += As[i][e] * Ws[j][e];
  const int h = col0 + j;
  xw[(size_t)(row0 + i) * H_ + h] = acc + b_ih[h] + b_hh[h];
}

// sc1 (MALL-coherent) relaxed atomic load — always-correct path
__device__ __forceinline__ u64 pload(const u64* p) {
  return __hip_atomic_load(p, __ATOMIC_RELAXED, __HIP_MEMORY_SCOPE_AGENT);
}
// sc0 (L1-bypass, L2-point) load/store — fast path within one XCD
__device__ __forceinline__ u64 load_sc0(const u64* p) {
  u64 r;
  asm volatile("global_load_dwordx2 %0, %1, off sc0\n\ts_waitcnt vmcnt(0)"
               : "=v"(r) : "v"(p) : "memory");
  return r;
}
__device__ __forceinline__ void store_sc0(u64* p, u64 v) {
  asm volatile("global_store_dwordx2 %0, %1, off sc0" :: "v"(p), "v"(v)
               : "memory");
}
// workgroup barrier WITHOUT vmcnt drain (LDS-ordered only). Safe here: all
// cross-thread data in k2 flows via LDS (lgkm-ordered) or via the
// self-synchronizing tagged mailboxes (no barrier needed).
__device__ __forceinline__ void lgkm_barrier() {
  asm volatile("s_waitcnt lgkmcnt(0)\n\ts_barrier" ::: "memory");
}

// ---------------------------------------------------------------------------
// K2: scan, WAVE-SPECIALIZED PUBLISHER experiment (r12 k2 is the fallback).
// r12's stall: vmcnt retires in-order per wave, and EVERY wave had q==0
// lanes issuing the sc1/MALL store -> every wave's first poll vmcnt(0)
// drained a ~900cy MALL ack each step. Fix: only wave 7 publishes, and
// wave 7 never waits on vmcnt (no polls); waves 0-6 poll but never store.
// Per step:
//   all: dot + shfl reduce; q==0 writes raw sum to sums[] (LDS); lgkm bar
//   wave7 (lanes 0-31): hn=tanh(xw+sums[lane]); sc0 publish; sc1 publish
//     (IMMEDIATELY, not deferred — r11's mistake); hs store; xw prefetch
//   waves0-6: poll all 512 words (tids<64 take 2), 64-iter fast bound +
//     sticky sc1 fallback (r8 logic verbatim), stage hp4
//   lgkm bar.
// Deadlock-free: publish(t) precedes end-barrier(t) within every block
// unconditionally -> inter-block wait chains ground at t=0. Slot reuse at
// distance 2: block passes end-bar(t+1) only after its pollers saw ALL 512
// tags t+1, whose publishers passed their polls at t -> every block
// consumed slot t before any publisher overwrites it at t+2.
// ---------------------------------------------------------------------------
__global__ __launch_bounds__(512) void k2_scan(
    const float* __restrict__ xw, const float* __restrict__ W_hh,
    float* __restrict__ hs, u64* __restrict__ part) {
  const int b = blockIdx.x & 15;  // batch -> XCD b%8 under round-robin
  const int g = blockIdx.x >> 4;  // slice
  const int tid = threadIdx.x;
  const int j = tid >> 4;         // 0..31 row within slice
  const int q = tid & 15;         // k-sixteenth
  const int wid = tid >> 6;
  const int lane = tid & 63;

  __shared__ f32x4 Wp[8 * 512];   // 64 KB, instruction-major W
  __shared__ f32x4 hp4[2][128];   // 4 KB, double-buffered h (i4-major)
  __shared__ float sums[JPB];     // raw dot sums for the publisher wave

  {
    const float* wrow = &W_hh[(size_t)(g * JPB + j) * H_ + q * 32];
#pragma unroll
    for (int i4 = 0; i4 < 8; ++i4)
      Wp[i4 * 512 + tid] = *(const f32x4*)&wrow[i4 * 4];
  }
  if (tid < 128) hp4[0][tid] = (f32x4)0.f;

  u64* const pf = part + (size_t)b * H_;             // +slot*B*H
  u64* const ps = part + (size_t)(2 * B_ + b) * H_;  // +slot*B*H

  // poller assignment: tid<448 polls word w1=tid; tid<64 also w2=448+tid.
  // hp4 float index for h word w: f(w) = ((w>>2)&7)*64 + (w>>5)*4 + (w&3)
  const int w1 = tid;
  const int w2 = 448 + tid;
  const int f1 = ((w1 >> 2) & 7) * 64 + (w1 >> 5) * 4 + (w1 & 3);
  const int f2 = ((w2 >> 2) & 7) * 64 + (w2 >> 5) * 4 + (w2 & 3);
  bool fast1 = true, fast2 = true;

  // publisher (wave 7, lanes 0-31) per-lane state
  float xwv = 0.f;
  if (wid == 7 && lane < 32)
    xwv = xw[(size_t)b * S_ * H_ + g * JPB + lane];
  __syncthreads();

  for (int t = 0; t < S_; ++t) {
    const int cur = t & 1;
    // dot: 8 x (b128 W read, b128 h broadcast, fma4)
    f32x4 a4 = (f32x4)0.f;
#pragma unroll
    for (int i4 = 0; i4 < 8; ++i4) {
      const f32x4 wv = Wp[i4 * 512 + tid];
      const f32x4 hv = hp4[cur][i4 * 16 + q];
      a4 += wv * hv;
    }
    float acc = a4.x + a4.y + a4.z + a4.w;
    acc += __shfl_xor(acc, 1);
    acc += __shfl_xor(acc, 2);
    acc += __shfl_xor(acc, 4);
    acc += __shfl_xor(acc, 8);
    if (q == 0) sums[j] = acc;
    lgkm_barrier();  // sums visible

    if (wid == 7) {
      if (lane < 32) {
        const int jp = g * JPB + lane;
        const float hn = tanhf(xwv + sums[lane]);  // vmcnt wait: last
                                                   // step's xw load (old)
        const u64 pk =
            ((u64)(unsigned)t << 32) | (u64)(unsigned)__float_as_uint(hn);
        store_sc0(&pf[(size_t)cur * (B_ * H_) + jp], pk);
        __hip_atomic_store(&ps[(size_t)cur * (B_ * H_) + jp], pk,
                           __ATOMIC_RELAXED, __HIP_MEMORY_SCOPE_AGENT);
        hs[((size_t)b * S_ + t) * H_ + jp] = hn;
        const int tn = (t + 1 < S_) ? t + 1 : t;
        xwv = xw[((size_t)b * S_ + tn) * H_ + jp];  // fire-and-forget
      }
    } else if (t + 1 < S_) {
      // word w1 (all pollers)
      {
        u64 v = 0;
        bool got = false;
        const u64* fw = &pf[(size_t)cur * (B_ * H_) + w1];
        if (fast1) {
          for (int it = 0; it < 64; ++it) {
            v = load_sc0(fw);
            if ((unsigned)(v >> 32) == (unsigned)t) { got = true; break; }
          }
          if (!got) fast1 = false;
        }
        if (!got) {
          const u64* sw = &ps[(size_t)cur * (B_ * H_) + w1];
          v = pload(sw);
          while ((unsigned)(v >> 32) != (unsigned)t) v = pload(sw);
        }
        ((float*)&hp4[cur ^ 1][0])[f1] = __uint_as_float((unsigned)v);
      }
      // word w2 (first 64 pollers)
      if (tid < 64) {
        u64 v = 0;
        bool got = false;
        const u64* fw = &pf[(size_t)cur * (B_ * H_) + w2];
        if (fast2) {
          for (int it = 0; it < 64; ++it) {
            v = load_sc0(fw);
            if ((unsigned)(v >> 32) == (unsigned)t) { got = true; break; }
          }
          if (!got) fast2 = false;
        }
        if (!got) {
          const u64* sw = &ps[(size_t)cur * (B_ * H_) + w2];
          v = pload(sw);
          while ((unsigned)(v >> 32) != (unsigned)t) v = pload(sw);
        }
        ((float*)&hp4[cur ^ 1][0])[f2] = __uint_as_float((unsigned)v);
      }
    }
    lgkm_barrier();  // hp4 staged
  }
}

// ---------------------------------------------------------------------------
// K5: split f32 -> bf16 hi + bf16 lo (RTN both; lo = f - hi).
// ---------------------------------------------------------------------------
__device__ __forceinline__ unsigned short bf16_rtn(float f) {
  unsigned u = __float_as_uint(f);
  return (unsigned short)((u + 0x7FFFu + ((u >> 16) & 1u)) >> 16);
}
__global__ __launch_bounds__(256) void k5_split(const float* __restrict__ src,
                                                unsigned short* __restrict__ hi,
                                                unsigned short* __restrict__ lo,
                                                int n4) {
  const int i = blockIdx.x * 256 + threadIdx.x;
  if (i >= n4) return;
  const float4 f = *(const float4*)&src[i * 4];
  unsigned short h[4], l[4];
  const float ff[4] = {f.x, f.y, f.z, f.w};
#pragma unroll
  for (int k = 0; k < 4; ++k) {
    h[k] = bf16_rtn(ff[k]);
    const float fh = __uint_as_float((unsigned)h[k] << 16);
    l[k] = bf16_rtn(ff[k] - fh);
  }
  *(ushort4*)&hi[i * 4] = make_ushort4(h[0], h[1], h[2], h[3]);
  *(ushort4*)&lo[i * 4] = make_ushort4(l[0], l[1], l[2], l[3]);
}

// ---------------------------------------------------------------------------
// K3: logits = hs @ W_fc^T + b_fc, bf16 hi/lo split MFMA (hh+hl+lh), PLUS
// fused softmax partials -> pstats[m_block][v] (banked r13).
// ---------------------------------------------------------------------------
__global__ __launch_bounds__(256) void k3_logits(
    const unsigned short* __restrict__ Ahi, const unsigned short* __restrict__ Alo,
    const unsigned short* __restrict__ Bhi, const unsigned short* __restrict__ Blo,
    const float* __restrict__ b_fc, float* __restrict__ out,
    float2* __restrict__ pstats) {
  __shared__ unsigned short Ah[128 * 32], Al[128 * 32];
  __shared__ unsigned short Bh[128 * 32], Bl[128 * 32];
  __shared__ float2 sstat[2][2][4][16];  // [wm][wn][ni][lr]
  const int m0 = blockIdx.x * 128;
  const int n0 = blockIdx.y * 128;
  const int tid = threadIdx.x;
  const int lane = tid & 63;
  const int wave = tid >> 6;
  const int wm = wave >> 1, wn = wave & 1;
  const int lr = lane & 15;
  const int lg = lane >> 4;
  const int cxr = (lg ^ (lr & 3)) * 8;  // swizzled k-chunk (shorts)

  const unsigned short* gp = (wave == 0) ? Ahi : (wave == 1) ? Alo
                           : (wave == 2) ? Bhi : Blo;
  unsigned short* lp = (wave == 0) ? Ah : (wave == 1) ? Al
                     : (wave == 2) ? Bh : Bl;
  const bool isB = wave >= 2;
  const int lrow = lane >> 2;
  const int lchunk = (lane & 3) ^ (lrow & 3);

  f32x4 acc[4][4];
#pragma unroll
  for (int mi = 0; mi < 4; ++mi)
#pragma unroll
    for (int ni = 0; ni < 4; ++ni) acc[mi][ni] = (f32x4)0.0f;

  for (int k0 = 0; k0 < H_; k0 += 32) {
    __syncthreads();
#pragma unroll
    for (int c16 = 0; c16 < 8; ++c16) {
      const int r = c16 * 16 + lrow;
      const int grow = isB ? min(n0 + r, V_ - 1) : (m0 + r);
      const unsigned short* src = gp + (size_t)grow * H_ + k0 + lchunk * 8;
      __builtin_amdgcn_global_load_lds(
          (const __attribute__((address_space(1))) void*)src,
          (__attribute__((address_space(3))) void*)(lp + c16 * 512), 16, 0, 0);
    }
    __syncthreads();

    bf16x8 ah[4], al[4], bh[4], bl[4];
#pragma unroll
    for (int i = 0; i < 4; ++i) {
      ah[i] = *(const bf16x8*)&Ah[(wm * 64 + i * 16 + lr) * 32 + cxr];
      al[i] = *(const bf16x8*)&Al[(wm * 64 + i * 16 + lr) * 32 + cxr];
      bh[i] = *(const bf16x8*)&Bh[(wn * 64 + i * 16 + lr) * 32 + cxr];
      bl[i] = *(const bf16x8*)&Bl[(wn * 64 + i * 16 + lr) * 32 + cxr];
    }
#pragma unroll
    for (int mi = 0; mi < 4; ++mi)
#pragma unroll
      for (int ni = 0; ni < 4; ++ni) {
        acc[mi][ni] = __builtin_amdgcn_mfma_f32_16x16x32_bf16(
            ah[mi], bh[ni], acc[mi][ni], 0, 0, 0);
        acc[mi][ni] = __builtin_amdgcn_mfma_f32_16x16x32_bf16(
            ah[mi], bl[ni], acc[mi][ni], 0, 0, 0);
        acc[mi][ni] = __builtin_amdgcn_mfma_f32_16x16x32_bf16(
            al[mi], bh[ni], acc[mi][ni], 0, 0, 0);
      }
  }

  // C-write (logits + bias)
#pragma unroll
  for (int ni = 0; ni < 4; ++ni) {
    const int v = n0 + wn * 64 + ni * 16 + lr;
    if (v >= V_) continue;
    const float bias = b_fc[v];
#pragma unroll
    for (int mi = 0; mi < 4; ++mi) {
      const int mrow = m0 + wm * 64 + mi * 16 + lg * 4;
#pragma unroll
      for (int r = 0; r < 4; ++r)
        out[(size_t)(mrow + r) * V_ + v] = acc[mi][ni][r] + bias;
    }
  }

  // fused softmax partials over this block's 128 rows (one batch slice)
  float pm[4], psum[4];
#pragma unroll
  for (int ni = 0; ni < 4; ++ni) {
    const int v = n0 + wn * 64 + ni * 16 + lr;
    float m = -3.4e38f, s = 0.f;
    if (v < V_) {
      const float bias = b_fc[v];
#pragma unroll
      for (int mi = 0; mi < 4; ++mi)
#pragma unroll
        for (int r = 0; r < 4; ++r)
          m = fmaxf(m, acc[mi][ni][r] + bias);
#pragma unroll
      for (int mi = 0; mi < 4; ++mi)
#pragma unroll
        for (int r = 0; r < 4; ++r)
          s += __expf(acc[mi][ni][r] + bias - m);
    }
#pragma unroll
    for (int d = 16; d <= 32; d <<= 1) {
      const float om = __shfl_xor(m, d);
      const float os = __shfl_xor(s, d);
      const float nm = fmaxf(m, om);
      s = s * __expf(m - nm) + os * __expf(om - nm);
      m = nm;
    }
    pm[ni] = m;
    psum[ni] = s;
  }
  __syncthreads();
  if (lg == 0) {
#pragma unroll
    for (int ni = 0; ni < 4; ++ni)
      sstat[wm][wn][ni][lr] = make_float2(pm[ni], psum[ni]);
  }
  __syncthreads();
  if (wm == 0 && lg == 0) {
#pragma unroll
    for (int ni = 0; ni < 4; ++ni) {
      const int v = n0 + wn * 64 + ni * 16 + lr;
      if (v < V_) {
        const float2 s0 = sstat[0][wn][ni][lr];
        const float2 s1 = sstat[1][wn][ni][lr];
        const float nm = fmaxf(s0.x, s1.x);
        const float ss =
            s0.y * __expf(s0.x - nm) + s1.y * __expf(s1.x - nm);
        pstats[(size_t)blockIdx.x * V_ + v] = make_float2(nm, ss);
      }
    }
  }
}

// ---------------------------------------------------------------------------
// K4a (merge): stats[b,v] = merge of 4 m-block partials.
// ---------------------------------------------------------------------------
__global__ __launch_bounds__(256) void k4_merge(const float2* __restrict__ pstats,
                                                float* __restrict__ stats) {
  const int gg = blockIdx.x * 256 + threadIdx.x;  // b*V + v, exact grid
  const int b = gg / V_;
  const int v = gg - b * V_;
  float m = -3.4e38f, s = 0.f;
#pragma unroll
  for (int i = 0; i < 4; ++i) {
    const float2 p = pstats[(size_t)(4 * b + i) * V_ + v];
    const float nm = fmaxf(m, p.x);
    s = s * __expf(m - nm) + p.y * __expf(p.x - nm);
    m = nm;
  }
  stats[2 * gg] = m;
  stats[2 * gg + 1] = 1.f / s;
}

// ---------------------------------------------------------------------------
// K4b: normalize, float4, no int-div: grid (ceil(V/1024), BS).
// ---------------------------------------------------------------------------
__global__ __launch_bounds__(256) void k4_norm(float* __restrict__ logits,
                                               const float* __restrict__ stats) {
  const int bs = blockIdx.y;
  const int b = bs >> 9;
  const int v0 = blockIdx.x * 1024 + threadIdx.x * 4;
  if (v0 >= V_) return;
  float* p = logits + (size_t)bs * V_ + v0;
  const float4 l = *(const float4*)p;
  const float4 s01 = *(const float4*)&stats[2 * (b * V_ + v0)];
  const float4 s23 = *(const float4*)&stats[2 * (b * V_ + v0) + 4];
  float4 o;
  o.x = __expf(l.x - s01.x) * s01.y;
  o.y = __expf(l.y - s01.z) * s01.w;
  o.z = __expf(l.z - s23.x) * s23.y;
  o.w = __expf(l.w - s23.z) * s23.w;
  *(float4*)p = o;
}

extern "C" void kernel_launch(void* const* d_in, const int* in_sizes, int n_in,
                              void* d_out, int out_size, void* d_ws,
                              size_t ws_size, hipStream_t stream) {
  const float* x    = (const float*)d_in[0];
  const float* W_ih = (const float*)d_in[1];
  const float* W_hh = (const float*)d_in[2];
  const float* b_ih = (const float*)d_in[3];
  const float* b_hh = (const float*)d_in[4];
  const float* W_fc = (const float*)d_in[5];
  const float* b_fc = (const float*)d_in[6];
  float* out = (float*)d_out;

  // ws layout (floats): xw | hs | stats | wfc_hi | wfc_lo | pstats
  //   part (256 KB, scan-only) ALIASES wfc_hi (k2 done before k5_wfc)
  //   hs_hi/hs_lo (bf16) ALIAS xw (dead after k2)
  float* ws = (float*)d_ws;
  float* xw    = ws;
  float* hs    = xw + (size_t)BS_ * H_;
  float* stats = hs + (size_t)BS_ * H_;
  unsigned short* wfc_hi = (unsigned short*)(stats + (size_t)2 * B_ * V_);
  unsigned short* wfc_lo = wfc_hi + (size_t)V_ * H_;
  float2* pstats = (float2*)(wfc_lo + (size_t)V_ * H_);  // 64*V float2
  u64* part = (u64*)wfc_hi;
  unsigned short* hs_hi = (unsigned short*)xw;
  unsigned short* hs_lo = hs_hi + (size_t)BS_ * H_;

  k0_init<<<PART_WORDS / 256, 256, 0, stream>>>(part);
  k1_xw<<<dim3(BS_ / 16, H_ / 16), 256, 0, stream>>>(x, W_ih, b_ih, b_hh, xw);
  k2_scan<<<NBLK, 512, 0, stream>>>(xw, W_hh, hs, part);
  k5_split<<<((V_ * H_ / 4) + 255) / 256, 256, 0, stream>>>(W_fc, wfc_hi,
                                                            wfc_lo, V_ * H_ / 4);
  k5_split<<<((BS_ * H_ / 4) + 255) / 256, 256, 0, stream>>>(
      hs, hs_hi, hs_lo, BS_ * H_ / 4);
  k3_logits<<<dim3(BS_ / 128, (V_ + 127) / 128), 256, 0, stream>>>(
      hs_hi, hs_lo, wfc_hi, wfc_lo, b_fc, out, pstats);
  k4_merge<<<(B_ * V_) / 256, 256, 0, stream>>>(pstats, stats);
  k4_norm<<<dim3((V_ + 1023) / 1024, BS_), 256, 0, stream>>>(out, stats);
}

// Round 15
// 1368.498 us; speedup vs baseline: 1.1056x; 1.1056x over previous
//
#include <hip/hip_runtime.h>
#include <hip/hip_bf16.h>
#include <math.h>

#define B_ 16
#define S_ 512
#define E_ 300
#define H_ 512
#define V_ 10000
#define BS_ (B_ * S_)  // 8192

#define NSL 16           // slices (blocks) per batch, j-split
#define JPB (H_ / NSL)   // 32 output rows per block
#define NBLK (B_ * NSL)  // 256 blocks in the scan

typedef __attribute__((ext_vector_type(4))) float f32x4;
typedef __attribute__((ext_vector_type(8))) short bf16x8;
typedef unsigned long long u64;

// part region: fast[2][B][H] | safe[2][B][H]
#define PART_WORDS (4 * B_ * H_)

// ---------------------------------------------------------------------------
// K0: invalidate exchange tags in BOTH mailboxes.
// ---------------------------------------------------------------------------
__global__ __launch_bounds__(256) void k0_init(u64* __restrict__ part) {
  const int idx = blockIdx.x * 256 + threadIdx.x;
  part[idx] = 0xFFFFFFFF00000000ull;
}

// ---------------------------------------------------------------------------
// K1: xw[bs,h] = sum_e x[bs,e] * W_ih[h,e] + b_ih[h] + b_hh[h]
// ---------------------------------------------------------------------------
__global__ __launch_bounds__(256) void k1_xw(const float* __restrict__ x,
                                             const float* __restrict__ W_ih,
                                             const float* __restrict__ b_ih,
                                             const float* __restrict__ b_hh,
                                             float* __restrict__ xw) {
  __shared__ float As[16][301];
  __shared__ float Ws[16][301];
  const int row0 = blockIdx.x * 16;
  const int col0 = blockIdx.y * 16;
  const int tid = threadIdx.x;
  for (int idx = tid; idx < 16 * E_; idx += 256) {
    int r = idx / E_, c = idx - r * E_;
    As[r][c] = x[(size_t)(row0 + r) * E_ + c];
    Ws[r][c] = W_ih[(size_t)(col0 + r) * E_ + c];
  }
  __syncthreads();
  const int i = tid >> 4, j = tid & 15;
  float acc = 0.f;
#pragma unroll 4
  for (int e = 0; e < E_; ++e) acc += As[i][e] * Ws[j][e];
  const int h = col0 + j;
  xw[(size_t)(row0 + i) * H_ + h] = acc + b_ih[h] + b_hh[h];
}

// sc1 (MALL-coherent) relaxed atomic load — always-correct path
__device__ __forceinline__ u64 pload(const u64* p) {
  return __hip_atomic_load(p, __ATOMIC_RELAXED, __HIP_MEMORY_SCOPE_AGENT);
}
// sc0 (L1-bypass, L2-point) load/store — fast path within one XCD
__device__ __forceinline__ u64 load_sc0(const u64* p) {
  u64 r;
  asm volatile("global_load_dwordx2 %0, %1, off sc0\n\ts_waitcnt vmcnt(0)"
               : "=v"(r) : "v"(p) : "memory");
  return r;
}
__device__ __forceinline__ void store_sc0(u64* p, u64 v) {
  asm volatile("global_store_dwordx2 %0, %1, off sc0" :: "v"(p), "v"(v)
               : "memory");
}

// ---------------------------------------------------------------------------
// K2: scan — ROUND-12 VERBATIM (banked: 692-699 us across r12/r13, FETCH
// 28.7 MB, conflicts 0). Failed deviations: r9 dual-batch (1650, serialized
// compute), r10 unbounded fast spin (hang), r11 deferred sc1 publish (1970,
// poisoned fallback), r14 wave-specialized publisher (878, publish behind
// block barrier -> sticky-downgrade cascade + staging conflicts).
// DO NOT MODIFY.
// ---------------------------------------------------------------------------
__global__ __launch_bounds__(512) void k2_scan(
    const float* __restrict__ xw, const float* __restrict__ W_hh,
    float* __restrict__ hs, u64* __restrict__ part) {
  const int b = blockIdx.x & 15;  // batch -> XCD b%8 under round-robin
  const int g = blockIdx.x >> 4;  // slice
  const int tid = threadIdx.x;
  const int j = tid >> 4;         // 0..31 row within slice
  const int q = tid & 15;         // k-sixteenth
  const int jg = g * JPB + j;     // global output row

  __shared__ f32x4 Wp[8 * 512];   // 64 KB, instruction-major W
  __shared__ f32x4 hp4[2][128];   // 4 KB, double-buffered h (i4-major)

  {
    const float* wrow = &W_hh[(size_t)jg * H_ + q * 32];
#pragma unroll
    for (int i4 = 0; i4 < 8; ++i4)
      Wp[i4 * 512 + tid] = *(const f32x4*)&wrow[i4 * 4];
  }
  if (tid < 128) hp4[0][tid] = (f32x4)0.f;

  u64* const pf = part + (size_t)b * H_;             // +slot*B*H
  u64* const ps = part + (size_t)(2 * B_ + b) * H_;  // +slot*B*H
  const int kk = ((tid & 63) >> 2) * 32 + (tid >> 6) * 4 + (tid & 3);
  bool fast = true;

  float xwv = xw[(size_t)b * S_ * H_ + jg];  // t = 0
  __syncthreads();

  for (int t = 0; t < S_; ++t) {
    const int cur = t & 1;
    f32x4 a4 = (f32x4)0.f;
#pragma unroll
    for (int i4 = 0; i4 < 8; ++i4) {
      const f32x4 wv = Wp[i4 * 512 + tid];
      const f32x4 hv = hp4[cur][i4 * 16 + q];
      a4 += wv * hv;
    }
    float acc = a4.x + a4.y + a4.z + a4.w;
    acc += __shfl_xor(acc, 1);
    acc += __shfl_xor(acc, 2);
    acc += __shfl_xor(acc, 4);
    acc += __shfl_xor(acc, 8);

    if (q == 0) {
      const float hn = tanhf(xwv + acc);
      const u64 pk =
          ((u64)(unsigned)t << 32) | (u64)(unsigned)__float_as_uint(hn);
      store_sc0(&pf[(size_t)cur * (B_ * H_) + jg], pk);
      __hip_atomic_store(&ps[(size_t)cur * (B_ * H_) + jg], pk,
                         __ATOMIC_RELAXED, __HIP_MEMORY_SCOPE_AGENT);
      hs[((size_t)b * S_ + t) * H_ + jg] = hn;
    }
    const int tn = (t + 1 < S_) ? t + 1 : t;
    const float xw_next = xw[((size_t)b * S_ + tn) * H_ + jg];

    if (t + 1 < S_) {
      u64 v = 0;
      bool got = false;
      const u64* fw = &pf[(size_t)cur * (B_ * H_) + kk];
      if (fast) {
        for (int it = 0; it < 64; ++it) {
          v = load_sc0(fw);
          if ((unsigned)(v >> 32) == (unsigned)t) { got = true; break; }
        }
        if (!got) fast = false;  // sticky downgrade (cross-XCD placement)
      }
      if (!got) {
        const u64* sw = &ps[(size_t)cur * (B_ * H_) + kk];
        v = pload(sw);
        while ((unsigned)(v >> 32) != (unsigned)t) v = pload(sw);
      }
      ((float*)&hp4[cur ^ 1][0])[tid] = __uint_as_float((unsigned)v);
    }
    xwv = xw_next;
    __syncthreads();
  }
}

// ---------------------------------------------------------------------------
// K5: split f32 -> bf16 hi + bf16 lo (RTN both; lo = f - hi).
// ---------------------------------------------------------------------------
__device__ __forceinline__ unsigned short bf16_rtn(float f) {
  unsigned u = __float_as_uint(f);
  return (unsigned short)((u + 0x7FFFu + ((u >> 16) & 1u)) >> 16);
}
__global__ __launch_bounds__(256) void k5_split(const float* __restrict__ src,
                                                unsigned short* __restrict__ hi,
                                                unsigned short* __restrict__ lo,
                                                int n4) {
  const int i = blockIdx.x * 256 + threadIdx.x;
  if (i >= n4) return;
  const float4 f = *(const float4*)&src[i * 4];
  unsigned short h[4], l[4];
  const float ff[4] = {f.x, f.y, f.z, f.w};
#pragma unroll
  for (int k = 0; k < 4; ++k) {
    h[k] = bf16_rtn(ff[k]);
    const float fh = __uint_as_float((unsigned)h[k] << 16);
    l[k] = bf16_rtn(ff[k] - fh);
  }
  *(ushort4*)&hi[i * 4] = make_ushort4(h[0], h[1], h[2], h[3]);
  *(ushort4*)&lo[i * 4] = make_ushort4(l[0], l[1], l[2], l[3]);
}

// ---------------------------------------------------------------------------
// K3: logits = hs @ W_fc^T + b_fc, bf16 hi/lo split MFMA (hh+hl+lh), fused
// softmax partials (banked r13), NOW 2-PHASE DOUBLE-BUFFERED (T3 minimum
// recipe): issue next k-step's global_load_lds BEFORE current ds_read+MFMA,
// ONE __syncthreads per k-step (was 2). LDS 33->66 KB (occupancy 3->2
// blocks/CU — grid 5056 blocks keeps TLP ample). Manual 2x unroll keeps
// buffer indices compile-time.
// ---------------------------------------------------------------------------
__global__ __launch_bounds__(256) void k3_logits(
    const unsigned short* __restrict__ Ahi, const unsigned short* __restrict__ Alo,
    const unsigned short* __restrict__ Bhi, const unsigned short* __restrict__ Blo,
    const float* __restrict__ b_fc, float* __restrict__ out,
    float2* __restrict__ pstats) {
  __shared__ unsigned short Ah[2][128 * 32], Al[2][128 * 32];
  __shared__ unsigned short Bh[2][128 * 32], Bl[2][128 * 32];
  __shared__ float2 sstat[2][2][4][16];  // [wm][wn][ni][lr]
  const int m0 = blockIdx.x * 128;
  const int n0 = blockIdx.y * 128;
  const int tid = threadIdx.x;
  const int lane = tid & 63;
  const int wave = tid >> 6;
  const int wm = wave >> 1, wn = wave & 1;
  const int lr = lane & 15;
  const int lg = lane >> 4;
  const int cxr = (lg ^ (lr & 3)) * 8;  // swizzled k-chunk (shorts)

  const unsigned short* gp = (wave == 0) ? Ahi : (wave == 1) ? Alo
                           : (wave == 2) ? Bhi : Blo;
  unsigned short* lp0 = (wave == 0) ? Ah[0] : (wave == 1) ? Al[0]
                      : (wave == 2) ? Bh[0] : Bl[0];
  unsigned short* lp1 = (wave == 0) ? Ah[1] : (wave == 1) ? Al[1]
                      : (wave == 2) ? Bh[1] : Bl[1];
  const bool isB = wave >= 2;
  const int lrow = lane >> 2;
  const int lchunk = (lane & 3) ^ (lrow & 3);

  f32x4 acc[4][4];
#pragma unroll
  for (int mi = 0; mi < 4; ++mi)
#pragma unroll
    for (int ni = 0; ni < 4; ++ni) acc[mi][ni] = (f32x4)0.0f;

  // stage k-step k0 into buffer dst (8 x global_load_lds width-16 per wave)
  auto STAGE = [&](int k0, unsigned short* dst) {
#pragma unroll
    for (int c16 = 0; c16 < 8; ++c16) {
      const int r = c16 * 16 + lrow;
      const int grow = isB ? min(n0 + r, V_ - 1) : (m0 + r);
      const unsigned short* src = gp + (size_t)grow * H_ + k0 + lchunk * 8;
      __builtin_amdgcn_global_load_lds(
          (const __attribute__((address_space(1))) void*)src,
          (__attribute__((address_space(3))) void*)(dst + c16 * 512), 16, 0, 0);
    }
  };
  // compute current buffer buf (frag reads + 48 MFMA)
  auto COMPUTE = [&](int buf) {
    bf16x8 ah[4], al[4], bh[4], bl[4];
#pragma unroll
    for (int i = 0; i < 4; ++i) {
      ah[i] = *(const bf16x8*)&Ah[buf][(wm * 64 + i * 16 + lr) * 32 + cxr];
      al[i] = *(const bf16x8*)&Al[buf][(wm * 64 + i * 16 + lr) * 32 + cxr];
      bh[i] = *(const bf16x8*)&Bh[buf][(wn * 64 + i * 16 + lr) * 32 + cxr];
      bl[i] = *(const bf16x8*)&Bl[buf][(wn * 64 + i * 16 + lr) * 32 + cxr];
    }
#pragma unroll
    for (int mi = 0; mi < 4; ++mi)
#pragma unroll
      for (int ni = 0; ni < 4; ++ni) {
        acc[mi][ni] = __builtin_amdgcn_mfma_f32_16x16x32_bf16(
            ah[mi], bh[ni], acc[mi][ni], 0, 0, 0);
        acc[mi][ni] = __builtin_amdgcn_mfma_f32_16x16x32_bf16(
            ah[mi], bl[ni], acc[mi][ni], 0, 0, 0);
        acc[mi][ni] = __builtin_amdgcn_mfma_f32_16x16x32_bf16(
            al[mi], bh[ni], acc[mi][ni], 0, 0, 0);
      }
  };

  // prologue: stage k=0 into buf0
  STAGE(0, lp0);
  __syncthreads();
  // 16 k-steps, 2 per unrolled iteration (compile-time buffer indices)
  for (int kt = 0; kt < 16; kt += 2) {
    // step A: read buf0, prefetch kt+1 into buf1
    STAGE((kt + 1) * 32, lp1);
    COMPUTE(0);
    __syncthreads();  // drains buf1 loads + buf0 reads
    // step B: read buf1, prefetch kt+2 into buf0
    if (kt + 2 < 16) STAGE((kt + 2) * 32, lp0);
    COMPUTE(1);
    __syncthreads();  // drains buf0 loads + buf1 reads
  }

  // C-write (logits + bias)
#pragma unroll
  for (int ni = 0; ni < 4; ++ni) {
    const int v = n0 + wn * 64 + ni * 16 + lr;
    if (v >= V_) continue;
    const float bias = b_fc[v];
#pragma unroll
    for (int mi = 0; mi < 4; ++mi) {
      const int mrow = m0 + wm * 64 + mi * 16 + lg * 4;
#pragma unroll
      for (int r = 0; r < 4; ++r)
        out[(size_t)(mrow + r) * V_ + v] = acc[mi][ni][r] + bias;
    }
  }

  // fused softmax partials over this block's 128 rows (one batch slice)
  float pm[4], psum[4];
#pragma unroll
  for (int ni = 0; ni < 4; ++ni) {
    const int v = n0 + wn * 64 + ni * 16 + lr;
    float m = -3.4e38f, s = 0.f;
    if (v < V_) {
      const float bias = b_fc[v];
#pragma unroll
      for (int mi = 0; mi < 4; ++mi)
#pragma unroll
        for (int r = 0; r < 4; ++r)
          m = fmaxf(m, acc[mi][ni][r] + bias);
#pragma unroll
      for (int mi = 0; mi < 4; ++mi)
#pragma unroll
        for (int r = 0; r < 4; ++r)
          s += __expf(acc[mi][ni][r] + bias - m);
    }
#pragma unroll
    for (int d = 16; d <= 32; d <<= 1) {
      const float om = __shfl_xor(m, d);
      const float os = __shfl_xor(s, d);
      const float nm = fmaxf(m, om);
      s = s * __expf(m - nm) + os * __expf(om - nm);
      m = nm;
    }
    pm[ni] = m;
    psum[ni] = s;
  }
  __syncthreads();
  if (lg == 0) {
#pragma unroll
    for (int ni = 0; ni < 4; ++ni)
      sstat[wm][wn][ni][lr] = make_float2(pm[ni], psum[ni]);
  }
  __syncthreads();
  if (wm == 0 && lg == 0) {
#pragma unroll
    for (int ni = 0; ni < 4; ++ni) {
      const int v = n0 + wn * 64 + ni * 16 + lr;
      if (v < V_) {
        const float2 s0 = sstat[0][wn][ni][lr];
        const float2 s1 = sstat[1][wn][ni][lr];
        const float nm = fmaxf(s0.x, s1.x);
        const float ss =
            s0.y * __expf(s0.x - nm) + s1.y * __expf(s1.x - nm);
        pstats[(size_t)blockIdx.x * V_ + v] = make_float2(nm, ss);
      }
    }
  }
}

// ---------------------------------------------------------------------------
// K4a (merge): stats[b,v] = merge of 4 m-block partials.
// ---------------------------------------------------------------------------
__global__ __launch_bounds__(256) void k4_merge(const float2* __restrict__ pstats,
                                                float* __restrict__ stats) {
  const int gg = blockIdx.x * 256 + threadIdx.x;  // b*V + v, exact grid
  const int b = gg / V_;
  const int v = gg - b * V_;
  float m = -3.4e38f, s = 0.f;
#pragma unroll
  for (int i = 0; i < 4; ++i) {
    const float2 p = pstats[(size_t)(4 * b + i) * V_ + v];
    const float nm = fmaxf(m, p.x);
    s = s * __expf(m - nm) + p.y * __expf(p.x - nm);
    m = nm;
  }
  stats[2 * gg] = m;
  stats[2 * gg + 1] = 1.f / s;
}

// ---------------------------------------------------------------------------
// K4b: normalize, float4, no int-div: grid (ceil(V/1024), BS).
// ---------------------------------------------------------------------------
__global__ __launch_bounds__(256) void k4_norm(float* __restrict__ logits,
                                               const float* __restrict__ stats) {
  const int bs = blockIdx.y;
  const int b = bs >> 9;
  const int v0 = blockIdx.x * 1024 + threadIdx.x * 4;
  if (v0 >= V_) return;
  float* p = logits + (size_t)bs * V_ + v0;
  const float4 l = *(const float4*)p;
  const float4 s01 = *(const float4*)&stats[2 * (b * V_ + v0)];
  const float4 s23 = *(const float4*)&stats[2 * (b * V_ + v0) + 4];
  float4 o;
  o.x = __expf(l.x - s01.x) * s01.y;
  o.y = __expf(l.y - s01.z) * s01.w;
  o.z = __expf(l.z - s23.x) * s23.y;
  o.w = __expf(l.w - s23.z) * s23.w;
  *(float4*)p = o;
}

extern "C" void kernel_launch(void* const* d_in, const int* in_sizes, int n_in,
                              void* d_out, int out_size, void* d_ws,
                              size_t ws_size, hipStream_t stream) {
  const float* x    = (const float*)d_in[0];
  const float* W_ih = (const float*)d_in[1];
  const float* W_hh = (const float*)d_in[2];
  const float* b_ih = (const float*)d_in[3];
  const float* b_hh = (const float*)d_in[4];
  const float* W_fc = (const float*)d_in[5];
  const float* b_fc = (const float*)d_in[6];
  float* out = (float*)d_out;

  // ws layout (floats): xw | hs | stats | wfc_hi | wfc_lo | pstats
  //   part (256 KB, scan-only) ALIASES wfc_hi (k2 done before k5_wfc)
  //   hs_hi/hs_lo (bf16) ALIAS xw (dead after k2)
  float* ws = (float*)d_ws;
  float* xw    = ws;
  float* hs    = xw + (size_t)BS_ * H_;
  float* stats = hs + (size_t)BS_ * H_;
  unsigned short* wfc_hi = (unsigned short*)(stats + (size_t)2 * B_ * V_);
  unsigned short* wfc_lo = wfc_hi + (size_t)V_ * H_;
  float2* pstats = (float2*)(wfc_lo + (size_t)V_ * H_);  // 64*V float2
  u64* part = (u64*)wfc_hi;
  unsigned short* hs_hi = (unsigned short*)xw;
  unsigned short* hs_lo = hs_hi + (size_t)BS_ * H_;

  k0_init<<<PART_WORDS / 256, 256, 0, stream>>>(part);
  k1_xw<<<dim3(BS_ / 16, H_ / 16), 256, 0, stream>>>(x, W_ih, b_ih, b_hh, xw);
  k2_scan<<<NBLK, 512, 0, stream>>>(xw, W_hh, hs, part);
  k5_split<<<((V_ * H_ / 4) + 255) / 256, 256, 0, stream>>>(W_fc, wfc_hi,
                                                            wfc_lo, V_ * H_ / 4);
  k5_split<<<((BS_ * H_ / 4) + 255) / 256, 256, 0, stream>>>(
      hs, hs_hi, hs_lo, BS_ * H_ / 4);
  k3_logits<<<dim3(BS_ / 128, (V_ + 127) / 128), 256, 0, stream>>>(
      hs_hi, hs_lo, wfc_hi, wfc_lo, b_fc, out, pstats);
  k4_merge<<<(B_ * V_) / 256, 256, 0, stream>>>(pstats, stats);
  k4_norm<<<dim3((V_ + 1023) / 1024, BS_), 256, 0, stream>>>(out, stats);
}

// Round 16
// 1306.337 us; speedup vs baseline: 1.1582x; 1.0476x over previous
//
#include <hip/hip_runtime.h>
#include <hip/hip_bf16.h>
#include <math.h>

#define B_ 16
#define S_ 512
#define E_ 300
#define H_ 512
#define V_ 10000
#define BS_ (B_ * S_)  // 8192

#define NSL 16           // slices (blocks) per batch, j-split
#define JPB (H_ / NSL)   // 32 output rows per block
#define NBLK (B_ * NSL)  // 256 blocks in the scan

typedef __attribute__((ext_vector_type(4))) float f32x4;
typedef __attribute__((ext_vector_type(8))) short bf16x8;
typedef unsigned long long u64;

// part region: fast[2][B][H] | safe[2][B][H]
#define PART_WORDS (4 * B_ * H_)

// ---------------------------------------------------------------------------
// K0: invalidate exchange tags in BOTH mailboxes.
// ---------------------------------------------------------------------------
__global__ __launch_bounds__(256) void k0_init(u64* __restrict__ part) {
  const int idx = blockIdx.x * 256 + threadIdx.x;
  part[idx] = 0xFFFFFFFF00000000ull;
}

// ---------------------------------------------------------------------------
// K1: xw[bs,h] = sum_e x[bs,e] * W_ih[h,e] + b_ih[h] + b_hh[h]
// 64x64 register-blocked tile (r16 rewrite): 16 outputs/thread (4x4),
// rows/cols strided by 16; f32x4 LDS reads (old 16x16 version was
// LDS-issue bound on scalar ds_read_b32: ~93us modeled). K chunked
// 152+148 (LDS 2x64x156 f32 = 78 KB). Bank analysis: As reads = 4 addrs
// x 16-lane broadcast, starts 28*ty%32 distinct -> conflict-free; Ws
// reads = 16 addrs, 8 distinct bank-starts -> 2-way (free, m136).
// ---------------------------------------------------------------------------
__global__ __launch_bounds__(256) void k1_xw(const float* __restrict__ x,
                                             const float* __restrict__ W_ih,
                                             const float* __restrict__ b_ih,
                                             const float* __restrict__ b_hh,
                                             float* __restrict__ xw) {
  __shared__ float As[64][156];
  __shared__ float Ws[64][156];
  const int row0 = blockIdx.x * 64;
  const int col0 = blockIdx.y * 64;
  const int tid = threadIdx.x;
  const int ty = tid >> 4, tx = tid & 15;
  float acc[4][4];
#pragma unroll
  for (int ii = 0; ii < 4; ++ii)
#pragma unroll
    for (int jj = 0; jj < 4; ++jj) acc[ii][jj] = 0.f;

  // ---- chunk 0: e in [0,152), 38 f32x4 per row ----
  for (int idx = tid; idx < 64 * 38; idx += 256) {
    const int r = idx / 38, e4 = idx - r * 38;
    *(float4*)&As[r][e4 * 4] =
        *(const float4*)&x[(size_t)(row0 + r) * E_ + e4 * 4];
    *(float4*)&Ws[r][e4 * 4] =
        *(const float4*)&W_ih[(size_t)(col0 + r) * E_ + e4 * 4];
  }
  __syncthreads();
#pragma unroll 2
  for (int e4 = 0; e4 < 38; ++e4) {
    f32x4 a[4], w[4];
#pragma unroll
    for (int ii = 0; ii < 4; ++ii)
      a[ii] = *(const f32x4*)&As[ty + 16 * ii][e4 * 4];
#pragma unroll
    for (int jj = 0; jj < 4; ++jj)
      w[jj] = *(const f32x4*)&Ws[tx + 16 * jj][e4 * 4];
#pragma unroll
    for (int ii = 0; ii < 4; ++ii)
#pragma unroll
      for (int jj = 0; jj < 4; ++jj) {
        const f32x4 p = a[ii] * w[jj];
        acc[ii][jj] += p.x + p.y + p.z + p.w;
      }
  }
  __syncthreads();

  // ---- chunk 1: e in [152,300), 37 f32x4 per row ----
  for (int idx = tid; idx < 64 * 37; idx += 256) {
    const int r = idx / 37, e4 = idx - r * 37;
    *(float4*)&As[r][e4 * 4] =
        *(const float4*)&x[(size_t)(row0 + r) * E_ + 152 + e4 * 4];
    *(float4*)&Ws[r][e4 * 4] =
        *(const float4*)&W_ih[(size_t)(col0 + r) * E_ + 152 + e4 * 4];
  }
  __syncthreads();
#pragma unroll 2
  for (int e4 = 0; e4 < 37; ++e4) {
    f32x4 a[4], w[4];
#pragma unroll
    for (int ii = 0; ii < 4; ++ii)
      a[ii] = *(const f32x4*)&As[ty + 16 * ii][e4 * 4];
#pragma unroll
    for (int jj = 0; jj < 4; ++jj)
      w[jj] = *(const f32x4*)&Ws[tx + 16 * jj][e4 * 4];
#pragma unroll
    for (int ii = 0; ii < 4; ++ii)
#pragma unroll
      for (int jj = 0; jj < 4; ++jj) {
        const f32x4 p = a[ii] * w[jj];
        acc[ii][jj] += p.x + p.y + p.z + p.w;
      }
  }

  // epilogue: add biases, write (coalesced 16-float runs per ty-group)
#pragma unroll
  for (int jj = 0; jj < 4; ++jj) {
    const int h = col0 + tx + 16 * jj;
    const float bb = b_ih[h] + b_hh[h];
#pragma unroll
    for (int ii = 0; ii < 4; ++ii)
      xw[(size_t)(row0 + ty + 16 * ii) * H_ + h] = acc[ii][jj] + bb;
  }
}

// sc1 (MALL-coherent) relaxed atomic load — always-correct path
__device__ __forceinline__ u64 pload(const u64* p) {
  return __hip_atomic_load(p, __ATOMIC_RELAXED, __HIP_MEMORY_SCOPE_AGENT);
}
// sc0 (L1-bypass, L2-point) load/store — fast path within one XCD
__device__ __forceinline__ u64 load_sc0(const u64* p) {
  u64 r;
  asm volatile("global_load_dwordx2 %0, %1, off sc0\n\ts_waitcnt vmcnt(0)"
               : "=v"(r) : "v"(p) : "memory");
  return r;
}
__device__ __forceinline__ void store_sc0(u64* p, u64 v) {
  asm volatile("global_store_dwordx2 %0, %1, off sc0" :: "v"(p), "v"(v)
               : "memory");
}

// ---------------------------------------------------------------------------
// K2: scan — ROUND-12 VERBATIM (banked: 692-700 us across r12/r13/r15,
// FETCH 28.7 MB, conflicts 0). Failed deviations: r9 dual-batch (1650),
// r10 unbounded fast spin (hang), r11 deferred sc1 publish (1970), r14
// wave-specialized publisher (878). DO NOT MODIFY.
// ---------------------------------------------------------------------------
__global__ __launch_bounds__(512) void k2_scan(
    const float* __restrict__ xw, const float* __restrict__ W_hh,
    float* __restrict__ hs, u64* __restrict__ part) {
  const int b = blockIdx.x & 15;  // batch -> XCD b%8 under round-robin
  const int g = blockIdx.x >> 4;  // slice
  const int tid = threadIdx.x;
  const int j = tid >> 4;         // 0..31 row within slice
  const int q = tid & 15;         // k-sixteenth
  const int jg = g * JPB + j;     // global output row

  __shared__ f32x4 Wp[8 * 512];   // 64 KB, instruction-major W
  __shared__ f32x4 hp4[2][128];   // 4 KB, double-buffered h (i4-major)

  {
    const float* wrow = &W_hh[(size_t)jg * H_ + q * 32];
#pragma unroll
    for (int i4 = 0; i4 < 8; ++i4)
      Wp[i4 * 512 + tid] = *(const f32x4*)&wrow[i4 * 4];
  }
  if (tid < 128) hp4[0][tid] = (f32x4)0.f;

  u64* const pf = part + (size_t)b * H_;             // +slot*B*H
  u64* const ps = part + (size_t)(2 * B_ + b) * H_;  // +slot*B*H
  const int kk = ((tid & 63) >> 2) * 32 + (tid >> 6) * 4 + (tid & 3);
  bool fast = true;

  float xwv = xw[(size_t)b * S_ * H_ + jg];  // t = 0
  __syncthreads();

  for (int t = 0; t < S_; ++t) {
    const int cur = t & 1;
    f32x4 a4 = (f32x4)0.f;
#pragma unroll
    for (int i4 = 0; i4 < 8; ++i4) {
      const f32x4 wv = Wp[i4 * 512 + tid];
      const f32x4 hv = hp4[cur][i4 * 16 + q];
      a4 += wv * hv;
    }
    float acc = a4.x + a4.y + a4.z + a4.w;
    acc += __shfl_xor(acc, 1);
    acc += __shfl_xor(acc, 2);
    acc += __shfl_xor(acc, 4);
    acc += __shfl_xor(acc, 8);

    if (q == 0) {
      const float hn = tanhf(xwv + acc);
      const u64 pk =
          ((u64)(unsigned)t << 32) | (u64)(unsigned)__float_as_uint(hn);
      store_sc0(&pf[(size_t)cur * (B_ * H_) + jg], pk);
      __hip_atomic_store(&ps[(size_t)cur * (B_ * H_) + jg], pk,
                         __ATOMIC_RELAXED, __HIP_MEMORY_SCOPE_AGENT);
      hs[((size_t)b * S_ + t) * H_ + jg] = hn;
    }
    const int tn = (t + 1 < S_) ? t + 1 : t;
    const float xw_next = xw[((size_t)b * S_ + tn) * H_ + jg];

    if (t + 1 < S_) {
      u64 v = 0;
      bool got = false;
      const u64* fw = &pf[(size_t)cur * (B_ * H_) + kk];
      if (fast) {
        for (int it = 0; it < 64; ++it) {
          v = load_sc0(fw);
          if ((unsigned)(v >> 32) == (unsigned)t) { got = true; break; }
        }
        if (!got) fast = false;  // sticky downgrade (cross-XCD placement)
      }
      if (!got) {
        const u64* sw = &ps[(size_t)cur * (B_ * H_) + kk];
        v = pload(sw);
        while ((unsigned)(v >> 32) != (unsigned)t) v = pload(sw);
      }
      ((float*)&hp4[cur ^ 1][0])[tid] = __uint_as_float((unsigned)v);
    }
    xwv = xw_next;
    __syncthreads();
  }
}

// ---------------------------------------------------------------------------
// K5: split f32 -> bf16 hi + bf16 lo (RTN both; lo = f - hi).
// ---------------------------------------------------------------------------
__device__ __forceinline__ unsigned short bf16_rtn(float f) {
  unsigned u = __float_as_uint(f);
  return (unsigned short)((u + 0x7FFFu + ((u >> 16) & 1u)) >> 16);
}
__global__ __launch_bounds__(256) void k5_split(const float* __restrict__ src,
                                                unsigned short* __restrict__ hi,
                                                unsigned short* __restrict__ lo,
                                                int n4) {
  const int i = blockIdx.x * 256 + threadIdx.x;
  if (i >= n4) return;
  const float4 f = *(const float4*)&src[i * 4];
  unsigned short h[4], l[4];
  const float ff[4] = {f.x, f.y, f.z, f.w};
#pragma unroll
  for (int k = 0; k < 4; ++k) {
    h[k] = bf16_rtn(ff[k]);
    const float fh = __uint_as_float((unsigned)h[k] << 16);
    l[k] = bf16_rtn(ff[k] - fh);
  }
  *(ushort4*)&hi[i * 4] = make_ushort4(h[0], h[1], h[2], h[3]);
  *(ushort4*)&lo[i * 4] = make_ushort4(l[0], l[1], l[2], l[3]);
}

// ---------------------------------------------------------------------------
// K3: logits = hs @ W_fc^T + b_fc, bf16 hi/lo split MFMA (hh+hl+lh), fused
// softmax partials (banked r13), 2-phase double-buffered (r15: neutral,
// kept as latest banked state).
// ---------------------------------------------------------------------------
__global__ __launch_bounds__(256) void k3_logits(
    const unsigned short* __restrict__ Ahi, const unsigned short* __restrict__ Alo,
    const unsigned short* __restrict__ Bhi, const unsigned short* __restrict__ Blo,
    const float* __restrict__ b_fc, float* __restrict__ out,
    float2* __restrict__ pstats) {
  __shared__ unsigned short Ah[2][128 * 32], Al[2][128 * 32];
  __shared__ unsigned short Bh[2][128 * 32], Bl[2][128 * 32];
  __shared__ float2 sstat[2][2][4][16];  // [wm][wn][ni][lr]
  const int m0 = blockIdx.x * 128;
  const int n0 = blockIdx.y * 128;
  const int tid = threadIdx.x;
  const int lane = tid & 63;
  const int wave = tid >> 6;
  const int wm = wave >> 1, wn = wave & 1;
  const int lr = lane & 15;
  const int lg = lane >> 4;
  const int cxr = (lg ^ (lr & 3)) * 8;  // swizzled k-chunk (shorts)

  const unsigned short* gp = (wave == 0) ? Ahi : (wave == 1) ? Alo
                           : (wave == 2) ? Bhi : Blo;
  unsigned short* lp0 = (wave == 0) ? Ah[0] : (wave == 1) ? Al[0]
                      : (wave == 2) ? Bh[0] : Bl[0];
  unsigned short* lp1 = (wave == 0) ? Ah[1] : (wave == 1) ? Al[1]
                      : (wave == 2) ? Bh[1] : Bl[1];
  const bool isB = wave >= 2;
  const int lrow = lane >> 2;
  const int lchunk = (lane & 3) ^ (lrow & 3);

  f32x4 acc[4][4];
#pragma unroll
  for (int mi = 0; mi < 4; ++mi)
#pragma unroll
    for (int ni = 0; ni < 4; ++ni) acc[mi][ni] = (f32x4)0.0f;

  auto STAGE = [&](int k0, unsigned short* dst) {
#pragma unroll
    for (int c16 = 0; c16 < 8; ++c16) {
      const int r = c16 * 16 + lrow;
      const int grow = isB ? min(n0 + r, V_ - 1) : (m0 + r);
      const unsigned short* src = gp + (size_t)grow * H_ + k0 + lchunk * 8;
      __builtin_amdgcn_global_load_lds(
          (const __attribute__((address_space(1))) void*)src,
          (__attribute__((address_space(3))) void*)(dst + c16 * 512), 16, 0, 0);
    }
  };
  auto COMPUTE = [&](int buf) {
    bf16x8 ah[4], al[4], bh[4], bl[4];
#pragma unroll
    for (int i = 0; i < 4; ++i) {
      ah[i] = *(const bf16x8*)&Ah[buf][(wm * 64 + i * 16 + lr) * 32 + cxr];
      al[i] = *(const bf16x8*)&Al[buf][(wm * 64 + i * 16 + lr) * 32 + cxr];
      bh[i] = *(const bf16x8*)&Bh[buf][(wn * 64 + i * 16 + lr) * 32 + cxr];
      bl[i] = *(const bf16x8*)&Bl[buf][(wn * 64 + i * 16 + lr) * 32 + cxr];
    }
#pragma unroll
    for (int mi = 0; mi < 4; ++mi)
#pragma unroll
      for (int ni = 0; ni < 4; ++ni) {
        acc[mi][ni] = __builtin_amdgcn_mfma_f32_16x16x32_bf16(
            ah[mi], bh[ni], acc[mi][ni], 0, 0, 0);
        acc[mi][ni] = __builtin_amdgcn_mfma_f32_16x16x32_bf16(
            ah[mi], bl[ni], acc[mi][ni], 0, 0, 0);
        acc[mi][ni] = __builtin_amdgcn_mfma_f32_16x16x32_bf16(
            al[mi], bh[ni], acc[mi][ni], 0, 0, 0);
      }
  };

  STAGE(0, lp0);
  __syncthreads();
  for (int kt = 0; kt < 16; kt += 2) {
    STAGE((kt + 1) * 32, lp1);
    COMPUTE(0);
    __syncthreads();
    if (kt + 2 < 16) STAGE((kt + 2) * 32, lp0);
    COMPUTE(1);
    __syncthreads();
  }

  // C-write (logits + bias)
#pragma unroll
  for (int ni = 0; ni < 4; ++ni) {
    const int v = n0 + wn * 64 + ni * 16 + lr;
    if (v >= V_) continue;
    const float bias = b_fc[v];
#pragma unroll
    for (int mi = 0; mi < 4; ++mi) {
      const int mrow = m0 + wm * 64 + mi * 16 + lg * 4;
#pragma unroll
      for (int r = 0; r < 4; ++r)
        out[(size_t)(mrow + r) * V_ + v] = acc[mi][ni][r] + bias;
    }
  }

  // fused softmax partials over this block's 128 rows (one batch slice)
  float pm[4], psum[4];
#pragma unroll
  for (int ni = 0; ni < 4; ++ni) {
    const int v = n0 + wn * 64 + ni * 16 + lr;
    float m = -3.4e38f, s = 0.f;
    if (v < V_) {
      const float bias = b_fc[v];
#pragma unroll
      for (int mi = 0; mi < 4; ++mi)
#pragma unroll
        for (int r = 0; r < 4; ++r)
          m = fmaxf(m, acc[mi][ni][r] + bias);
#pragma unroll
      for (int mi = 0; mi < 4; ++mi)
#pragma unroll
        for (int r = 0; r < 4; ++r)
          s += __expf(acc[mi][ni][r] + bias - m);
    }
#pragma unroll
    for (int d = 16; d <= 32; d <<= 1) {
      const float om = __shfl_xor(m, d);
      const float os = __shfl_xor(s, d);
      const float nm = fmaxf(m, om);
      s = s * __expf(m - nm) + os * __expf(om - nm);
      m = nm;
    }
    pm[ni] = m;
    psum[ni] = s;
  }
  __syncthreads();
  if (lg == 0) {
#pragma unroll
    for (int ni = 0; ni < 4; ++ni)
      sstat[wm][wn][ni][lr] = make_float2(pm[ni], psum[ni]);
  }
  __syncthreads();
  if (wm == 0 && lg == 0) {
#pragma unroll
    for (int ni = 0; ni < 4; ++ni) {
      const int v = n0 + wn * 64 + ni * 16 + lr;
      if (v < V_) {
        const float2 s0 = sstat[0][wn][ni][lr];
        const float2 s1 = sstat[1][wn][ni][lr];
        const float nm = fmaxf(s0.x, s1.x);
        const float ss =
            s0.y * __expf(s0.x - nm) + s1.y * __expf(s1.x - nm);
        pstats[(size_t)blockIdx.x * V_ + v] = make_float2(nm, ss);
      }
    }
  }
}

// ---------------------------------------------------------------------------
// K4a (merge): stats[b,v] = merge of 4 m-block partials.
// ---------------------------------------------------------------------------
__global__ __launch_bounds__(256) void k4_merge(const float2* __restrict__ pstats,
                                                float* __restrict__ stats) {
  const int gg = blockIdx.x * 256 + threadIdx.x;  // b*V + v, exact grid
  const int b = gg / V_;
  const int v = gg - b * V_;
  float m = -3.4e38f, s = 0.f;
#pragma unroll
  for (int i = 0; i < 4; ++i) {
    const float2 p = pstats[(size_t)(4 * b + i) * V_ + v];
    const float nm = fmaxf(m, p.x);
    s = s * __expf(m - nm) + p.y * __expf(p.x - nm);
    m = nm;
  }
  stats[2 * gg] = m;
  stats[2 * gg + 1] = 1.f / s;
}

// ---------------------------------------------------------------------------
// K4b: normalize, 8 floats/thread (2x float4), no int-div.
// grid (ceil(V/2048), BS). V%8==0 so both float4s are in-bounds when v0<V.
// ---------------------------------------------------------------------------
__global__ __launch_bounds__(256) void k4_norm(float* __restrict__ logits,
                                               const float* __restrict__ stats) {
  const int bs = blockIdx.y;
  const int b = bs >> 9;
  const int v0 = blockIdx.x * 2048 + threadIdx.x * 8;
  if (v0 >= V_) return;
  float* p = logits + (size_t)bs * V_ + v0;
  const float* st = stats + 2 * (b * V_ + v0);
  const float4 l0 = *(const float4*)&p[0];
  const float4 l1 = *(const float4*)&p[4];
  const float4 s0 = *(const float4*)&st[0];
  const float4 s1 = *(const float4*)&st[4];
  const float4 s2 = *(const float4*)&st[8];
  const float4 s3 = *(const float4*)&st[12];
  float4 o0, o1;
  o0.x = __expf(l0.x - s0.x) * s0.y;
  o0.y = __expf(l0.y - s0.z) * s0.w;
  o0.z = __expf(l0.z - s1.x) * s1.y;
  o0.w = __expf(l0.w - s1.z) * s1.w;
  o1.x = __expf(l1.x - s2.x) * s2.y;
  o1.y = __expf(l1.y - s2.z) * s2.w;
  o1.z = __expf(l1.z - s3.x) * s3.y;
  o1.w = __expf(l1.w - s3.z) * s3.w;
  *(float4*)&p[0] = o0;
  *(float4*)&p[4] = o1;
}

extern "C" void kernel_launch(void* const* d_in, const int* in_sizes, int n_in,
                              void* d_out, int out_size, void* d_ws,
                              size_t ws_size, hipStream_t stream) {
  const float* x    = (const float*)d_in[0];
  const float* W_ih = (const float*)d_in[1];
  const float* W_hh = (const float*)d_in[2];
  const float* b_ih = (const float*)d_in[3];
  const float* b_hh = (const float*)d_in[4];
  const float* W_fc = (const float*)d_in[5];
  const float* b_fc = (const float*)d_in[6];
  float* out = (float*)d_out;

  // ws layout (floats): xw | hs | stats | wfc_hi | wfc_lo | pstats
  //   part (256 KB, scan-only) ALIASES wfc_hi (k2 done before k5_wfc)
  //   hs_hi/hs_lo (bf16) ALIAS xw (dead after k2)
  float* ws = (float*)d_ws;
  float* xw    = ws;
  float* hs    = xw + (size_t)BS_ * H_;
  float* stats = hs + (size_t)BS_ * H_;
  unsigned short* wfc_hi = (unsigned short*)(stats + (size_t)2 * B_ * V_);
  unsigned short* wfc_lo = wfc_hi + (size_t)V_ * H_;
  float2* pstats = (float2*)(wfc_lo + (size_t)V_ * H_);  // 64*V float2
  u64* part = (u64*)wfc_hi;
  unsigned short* hs_hi = (unsigned short*)xw;
  unsigned short* hs_lo = hs_hi + (size_t)BS_ * H_;

  k0_init<<<PART_WORDS / 256, 256, 0, stream>>>(part);
  k1_xw<<<dim3(BS_ / 64, H_ / 64), 256, 0, stream>>>(x, W_ih, b_ih, b_hh, xw);
  k2_scan<<<NBLK, 512, 0, stream>>>(xw, W_hh, hs, part);
  k5_split<<<((V_ * H_ / 4) + 255) / 256, 256, 0, stream>>>(W_fc, wfc_hi,
                                                            wfc_lo, V_ * H_ / 4);
  k5_split<<<((BS_ * H_ / 4) + 255) / 256, 256, 0, stream>>>(
      hs, hs_hi, hs_lo, BS_ * H_ / 4);
  k3_logits<<<dim3(BS_ / 128, (V_ + 127) / 128), 256, 0, stream>>>(
      hs_hi, hs_lo, wfc_hi, wfc_lo, b_fc, out, pstats);
  k4_merge<<<(B_ * V_) / 256, 256, 0, stream>>>(pstats, stats);
  k4_norm<<<dim3((V_ + 2047) / 2048, BS_), 256, 0, stream>>>(out, stats);
}

// Round 17
// 1288.758 us; speedup vs baseline: 1.1740x; 1.0136x over previous
//
#include <hip/hip_runtime.h>
#include <hip/hip_bf16.h>
#include <math.h>

#define B_ 16
#define S_ 512
#define E_ 300
#define H_ 512
#define V_ 10000
#define BS_ (B_ * S_)  // 8192

#define NSL 16           // slices (blocks) per batch, j-split
#define JPB (H_ / NSL)   // 32 output rows per block
#define NBLK (B_ * NSL)  // 256 blocks in the scan

typedef __attribute__((ext_vector_type(4))) float f32x4;
typedef __attribute__((ext_vector_type(8))) short bf16x8;
typedef unsigned long long u64;

// part region: fast[2][B][H] | safe[2][B][H]
#define PART_WORDS (4 * B_ * H_)

// ---------------------------------------------------------------------------
// K0: invalidate exchange tags in BOTH mailboxes.
// ---------------------------------------------------------------------------
__global__ __launch_bounds__(256) void k0_init(u64* __restrict__ part) {
  const int idx = blockIdx.x * 256 + threadIdx.x;
  part[idx] = 0xFFFFFFFF00000000ull;
}

// ---------------------------------------------------------------------------
// K1: xw = x @ W_ih^T + biases. 64x64 register-blocked (banked r16).
// ---------------------------------------------------------------------------
__global__ __launch_bounds__(256) void k1_xw(const float* __restrict__ x,
                                             const float* __restrict__ W_ih,
                                             const float* __restrict__ b_ih,
                                             const float* __restrict__ b_hh,
                                             float* __restrict__ xw) {
  __shared__ float As[64][156];
  __shared__ float Ws[64][156];
  const int row0 = blockIdx.x * 64;
  const int col0 = blockIdx.y * 64;
  const int tid = threadIdx.x;
  const int ty = tid >> 4, tx = tid & 15;
  float acc[4][4];
#pragma unroll
  for (int ii = 0; ii < 4; ++ii)
#pragma unroll
    for (int jj = 0; jj < 4; ++jj) acc[ii][jj] = 0.f;

  for (int idx = tid; idx < 64 * 38; idx += 256) {
    const int r = idx / 38, e4 = idx - r * 38;
    *(float4*)&As[r][e4 * 4] =
        *(const float4*)&x[(size_t)(row0 + r) * E_ + e4 * 4];
    *(float4*)&Ws[r][e4 * 4] =
        *(const float4*)&W_ih[(size_t)(col0 + r) * E_ + e4 * 4];
  }
  __syncthreads();
#pragma unroll 2
  for (int e4 = 0; e4 < 38; ++e4) {
    f32x4 a[4], w[4];
#pragma unroll
    for (int ii = 0; ii < 4; ++ii)
      a[ii] = *(const f32x4*)&As[ty + 16 * ii][e4 * 4];
#pragma unroll
    for (int jj = 0; jj < 4; ++jj)
      w[jj] = *(const f32x4*)&Ws[tx + 16 * jj][e4 * 4];
#pragma unroll
    for (int ii = 0; ii < 4; ++ii)
#pragma unroll
      for (int jj = 0; jj < 4; ++jj) {
        const f32x4 p = a[ii] * w[jj];
        acc[ii][jj] += p.x + p.y + p.z + p.w;
      }
  }
  __syncthreads();

  for (int idx = tid; idx < 64 * 37; idx += 256) {
    const int r = idx / 37, e4 = idx - r * 37;
    *(float4*)&As[r][e4 * 4] =
        *(const float4*)&x[(size_t)(row0 + r) * E_ + 152 + e4 * 4];
    *(float4*)&Ws[r][e4 * 4] =
        *(const float4*)&W_ih[(size_t)(col0 + r) * E_ + 152 + e4 * 4];
  }
  __syncthreads();
#pragma unroll 2
  for (int e4 = 0; e4 < 37; ++e4) {
    f32x4 a[4], w[4];
#pragma unroll
    for (int ii = 0; ii < 4; ++ii)
      a[ii] = *(const f32x4*)&As[ty + 16 * ii][e4 * 4];
#pragma unroll
    for (int jj = 0; jj < 4; ++jj)
      w[jj] = *(const f32x4*)&Ws[tx + 16 * jj][e4 * 4];
#pragma unroll
    for (int ii = 0; ii < 4; ++ii)
#pragma unroll
      for (int jj = 0; jj < 4; ++jj) {
        const f32x4 p = a[ii] * w[jj];
        acc[ii][jj] += p.x + p.y + p.z + p.w;
      }
  }

#pragma unroll
  for (int jj = 0; jj < 4; ++jj) {
    const int h = col0 + tx + 16 * jj;
    const float bb = b_ih[h] + b_hh[h];
#pragma unroll
    for (int ii = 0; ii < 4; ++ii)
      xw[(size_t)(row0 + ty + 16 * ii) * H_ + h] = acc[ii][jj] + bb;
  }
}

// sc1 (MALL-coherent) relaxed atomic load — always-correct path
__device__ __forceinline__ u64 pload(const u64* p) {
  return __hip_atomic_load(p, __ATOMIC_RELAXED, __HIP_MEMORY_SCOPE_AGENT);
}
// sc0 (L1-bypass, L2-point) load/store — fast path within one XCD
__device__ __forceinline__ u64 load_sc0(const u64* p) {
  u64 r;
  asm volatile("global_load_dwordx2 %0, %1, off sc0\n\ts_waitcnt vmcnt(0)"
               : "=v"(r) : "v"(p) : "memory");
  return r;
}
__device__ __forceinline__ void store_sc0(u64* p, u64 v) {
  asm volatile("global_store_dwordx2 %0, %1, off sc0" :: "v"(p), "v"(v)
               : "memory");
}
// workgroup barrier WITHOUT vmcnt drain (LDS-ordered only). Safe in k2: all
// cross-thread data flows via LDS (lgkm-ordered) or the tag-synchronized
// mailboxes. Crucially, does NOT force wave 8 to drain its MALL acks.
__device__ __forceinline__ void lgkm_barrier() {
  asm volatile("s_waitcnt lgkmcnt(0)\n\ts_barrier" ::: "memory");
}

// ---------------------------------------------------------------------------
// K2: scan — r12 skeleton + 9th "insurance wave" (r17 experiment).
// Diagnosis (r12 counters + r14): vmcnt retires IN ORDER per wave; in the
// r8/r12 form every wave's q==0 lanes issue the sc1/MALL store, so every
// first poll's vmcnt(0) drains a ~900cy MALL ack. r14 failed by delaying
// the sc0 fast publish behind a block barrier (fast-path collapse). Here:
//   waves 0-7 (512 thr): dot -> shfl reduce -> q==0: tanh + sc0 publish
//     IMMEDIATELY (r8 timing preserved) + hname[j]=hn (LDS) + xw prefetch
//   lgkm barrier
//   wave 8 lanes 0-31: read hname, fire-and-forget sc1 publish + hs store
//     (never waits on vmcnt; ~4 outstanding acks steady-state)
//   waves 0-7: poll (64-iter sc0 bound + sticky sc1 fallback, r8 verbatim)
//     — their queues now hold only sc0-ack (~250cy) + xw load
//   lgkm barrier.
// Deadlock-free: sc1(t) issues unconditionally after own mid-step barrier
// (depends only on own dot, never any poll) -> induction grounds at t=0.
// Slot distance-2 (both mailboxes): partner read slot-t before its end-
// bar(t) < its publish(t+1) <= our end-bar(t+1) < our overwrite(t+2).
// Fallback latency: sc1(t) lands ~1 barrier later than r8 — SLOW mode a
// bit slower, FAST mode (engaged in all r8-r16 runs; FETCH 28MB) faster.
// ---------------------------------------------------------------------------
__global__ __launch_bounds__(576) void k2_scan(
    const float* __restrict__ xw, const float* __restrict__ W_hh,
    float* __restrict__ hs, u64* __restrict__ part) {
  const int b = blockIdx.x & 15;  // batch -> XCD b%8 under round-robin
  const int g = blockIdx.x >> 4;  // slice
  const int tid = threadIdx.x;
  const int wid = tid >> 6;
  const int lane = tid & 63;
  const int j = tid >> 4;         // 0..31 (valid for tid<512)
  const int q = tid & 15;
  const int jg = g * JPB + j;

  __shared__ f32x4 Wp[8 * 512];   // 64 KB, instruction-major W
  __shared__ f32x4 hp4[2][128];   // 4 KB, double-buffered h (i4-major)
  __shared__ float hname[JPB];    // this step's fresh h values

  if (tid < 512) {
    const float* wrow = &W_hh[(size_t)jg * H_ + q * 32];
#pragma unroll
    for (int i4 = 0; i4 < 8; ++i4)
      Wp[i4 * 512 + tid] = *(const f32x4*)&wrow[i4 * 4];
  }
  if (tid < 128) hp4[0][tid] = (f32x4)0.f;

  u64* const pf = part + (size_t)b * H_;             // +slot*B*H
  u64* const ps = part + (size_t)(2 * B_ + b) * H_;  // +slot*B*H
  const int kk = ((tid & 63) >> 2) * 32 + (tid >> 6) * 4 + (tid & 3);
  bool fast = true;

  float xwv = (tid < 512) ? xw[(size_t)b * S_ * H_ + jg] : 0.f;
  __syncthreads();

  for (int t = 0; t < S_; ++t) {
    const int cur = t & 1;
    if (tid < 512) {
      f32x4 a4 = (f32x4)0.f;
#pragma unroll
      for (int i4 = 0; i4 < 8; ++i4) {
        const f32x4 wv = Wp[i4 * 512 + tid];
        const f32x4 hv = hp4[cur][i4 * 16 + q];
        a4 += wv * hv;
      }
      float acc = a4.x + a4.y + a4.z + a4.w;
      acc += __shfl_xor(acc, 1);
      acc += __shfl_xor(acc, 2);
      acc += __shfl_xor(acc, 4);
      acc += __shfl_xor(acc, 8);
      if (q == 0) {
        const float hn = tanhf(xwv + acc);
        store_sc0(&pf[(size_t)cur * (B_ * H_) + jg],
                  ((u64)(unsigned)t << 32) | (u64)(unsigned)__float_as_uint(hn));
        hname[j] = hn;
        const int tn = (t + 1 < S_) ? t + 1 : t;
        xwv = xw[((size_t)b * S_ + tn) * H_ + jg];  // prefetch
      }
    }
    lgkm_barrier();  // hname visible to wave 8

    if (wid == 8) {
      if (lane < JPB) {
        const int jp = g * JPB + lane;
        const float hn = hname[lane];
        const u64 pk =
            ((u64)(unsigned)t << 32) | (u64)(unsigned)__float_as_uint(hn);
        __hip_atomic_store(&ps[(size_t)cur * (B_ * H_) + jp], pk,
                           __ATOMIC_RELAXED, __HIP_MEMORY_SCOPE_AGENT);
        hs[((size_t)b * S_ + t) * H_ + jp] = hn;
        // fire-and-forget: wave 8 never executes a vmcnt wait
      }
    } else if (t + 1 < S_) {
      u64 v = 0;
      bool got = false;
      const u64* fw = &pf[(size_t)cur * (B_ * H_) + kk];
      if (fast) {
        for (int it = 0; it < 64; ++it) {
          v = load_sc0(fw);
          if ((unsigned)(v >> 32) == (unsigned)t) { got = true; break; }
        }
        if (!got) fast = false;  // sticky downgrade (cross-XCD placement)
      }
      if (!got) {
        const u64* sw = &ps[(size_t)cur * (B_ * H_) + kk];
        v = pload(sw);
        while ((unsigned)(v >> 32) != (unsigned)t) v = pload(sw);
      }
      ((float*)&hp4[cur ^ 1][0])[tid] = __uint_as_float((unsigned)v);
    }
    lgkm_barrier();  // hp4 staged; no vmcnt drain (wave 8 acks float free)
  }
}

// ---------------------------------------------------------------------------
// K5: split f32 -> bf16 hi + bf16 lo (RTN both; lo = f - hi).
// ---------------------------------------------------------------------------
__device__ __forceinline__ unsigned short bf16_rtn(float f) {
  unsigned u = __float_as_uint(f);
  return (unsigned short)((u + 0x7FFFu + ((u >> 16) & 1u)) >> 16);
}
__global__ __launch_bounds__(256) void k5_split(const float* __restrict__ src,
                                                unsigned short* __restrict__ hi,
                                                unsigned short* __restrict__ lo,
                                                int n4) {
  const int i = blockIdx.x * 256 + threadIdx.x;
  if (i >= n4) return;
  const float4 f = *(const float4*)&src[i * 4];
  unsigned short h[4], l[4];
  const float ff[4] = {f.x, f.y, f.z, f.w};
#pragma unroll
  for (int k = 0; k < 4; ++k) {
    h[k] = bf16_rtn(ff[k]);
    const float fh = __uint_as_float((unsigned)h[k] << 16);
    l[k] = bf16_rtn(ff[k] - fh);
  }
  *(ushort4*)&hi[i * 4] = make_ushort4(h[0], h[1], h[2], h[3]);
  *(ushort4*)&lo[i * 4] = make_ushort4(l[0], l[1], l[2], l[3]);
}

// ---------------------------------------------------------------------------
// K3: logits = hs @ W_fc^T + b_fc, bf16 hi/lo split MFMA (hh+hl+lh), fused
// softmax partials, 2-phase double-buffered (banked r13/r15).
// ---------------------------------------------------------------------------
__global__ __launch_bounds__(256) void k3_logits(
    const unsigned short* __restrict__ Ahi, const unsigned short* __restrict__ Alo,
    const unsigned short* __restrict__ Bhi, const unsigned short* __restrict__ Blo,
    const float* __restrict__ b_fc, float* __restrict__ out,
    float2* __restrict__ pstats) {
  __shared__ unsigned short Ah[2][128 * 32], Al[2][128 * 32];
  __shared__ unsigned short Bh[2][128 * 32], Bl[2][128 * 32];
  __shared__ float2 sstat[2][2][4][16];  // [wm][wn][ni][lr]
  const int m0 = blockIdx.x * 128;
  const int n0 = blockIdx.y * 128;
  const int tid = threadIdx.x;
  const int lane = tid & 63;
  const int wave = tid >> 6;
  const int wm = wave >> 1, wn = wave & 1;
  const int lr = lane & 15;
  const int lg = lane >> 4;
  const int cxr = (lg ^ (lr & 3)) * 8;  // swizzled k-chunk (shorts)

  const unsigned short* gp = (wave == 0) ? Ahi : (wave == 1) ? Alo
                           : (wave == 2) ? Bhi : Blo;
  unsigned short* lp0 = (wave == 0) ? Ah[0] : (wave == 1) ? Al[0]
                      : (wave == 2) ? Bh[0] : Bl[0];
  unsigned short* lp1 = (wave == 0) ? Ah[1] : (wave == 1) ? Al[1]
                      : (wave == 2) ? Bh[1] : Bl[1];
  const bool isB = wave >= 2;
  const int lrow = lane >> 2;
  const int lchunk = (lane & 3) ^ (lrow & 3);

  f32x4 acc[4][4];
#pragma unroll
  for (int mi = 0; mi < 4; ++mi)
#pragma unroll
    for (int ni = 0; ni < 4; ++ni) acc[mi][ni] = (f32x4)0.0f;

  auto STAGE = [&](int k0, unsigned short* dst) {
#pragma unroll
    for (int c16 = 0; c16 < 8; ++c16) {
      const int r = c16 * 16 + lrow;
      const int grow = isB ? min(n0 + r, V_ - 1) : (m0 + r);
      const unsigned short* src = gp + (size_t)grow * H_ + k0 + lchunk * 8;
      __builtin_amdgcn_global_load_lds(
          (const __attribute__((address_space(1))) void*)src,
          (__attribute__((address_space(3))) void*)(dst + c16 * 512), 16, 0, 0);
    }
  };
  auto COMPUTE = [&](int buf) {
    bf16x8 ah[4], al[4], bh[4], bl[4];
#pragma unroll
    for (int i = 0; i < 4; ++i) {
      ah[i] = *(const bf16x8*)&Ah[buf][(wm * 64 + i * 16 + lr) * 32 + cxr];
      al[i] = *(const bf16x8*)&Al[buf][(wm * 64 + i * 16 + lr) * 32 + cxr];
      bh[i] = *(const bf16x8*)&Bh[buf][(wn * 64 + i * 16 + lr) * 32 + cxr];
      bl[i] = *(const bf16x8*)&Bl[buf][(wn * 64 + i * 16 + lr) * 32 + cxr];
    }
#pragma unroll
    for (int mi = 0; mi < 4; ++mi)
#pragma unroll
      for (int ni = 0; ni < 4; ++ni) {
        acc[mi][ni] = __builtin_amdgcn_mfma_f32_16x16x32_bf16(
            ah[mi], bh[ni], acc[mi][ni], 0, 0, 0);
        acc[mi][ni] = __builtin_amdgcn_mfma_f32_16x16x32_bf16(
            ah[mi], bl[ni], acc[mi][ni], 0, 0, 0);
        acc[mi][ni] = __builtin_amdgcn_mfma_f32_16x16x32_bf16(
            al[mi], bh[ni], acc[mi][ni], 0, 0, 0);
      }
  };

  STAGE(0, lp0);
  __syncthreads();
  for (int kt = 0; kt < 16; kt += 2) {
    STAGE((kt + 1) * 32, lp1);
    COMPUTE(0);
    __syncthreads();
    if (kt + 2 < 16) STAGE((kt + 2) * 32, lp0);
    COMPUTE(1);
    __syncthreads();
  }

#pragma unroll
  for (int ni = 0; ni < 4; ++ni) {
    const int v = n0 + wn * 64 + ni * 16 + lr;
    if (v >= V_) continue;
    const float bias = b_fc[v];
#pragma unroll
    for (int mi = 0; mi < 4; ++mi) {
      const int mrow = m0 + wm * 64 + mi * 16 + lg * 4;
#pragma unroll
      for (int r = 0; r < 4; ++r)
        out[(size_t)(mrow + r) * V_ + v] = acc[mi][ni][r] + bias;
    }
  }

  float pm[4], psum[4];
#pragma unroll
  for (int ni = 0; ni < 4; ++ni) {
    const int v = n0 + wn * 64 + ni * 16 + lr;
    float m = -3.4e38f, s = 0.f;
    if (v < V_) {
      const float bias = b_fc[v];
#pragma unroll
      for (int mi = 0; mi < 4; ++mi)
#pragma unroll
        for (int r = 0; r < 4; ++r)
          m = fmaxf(m, acc[mi][ni][r] + bias);
#pragma unroll
      for (int mi = 0; mi < 4; ++mi)
#pragma unroll
        for (int r = 0; r < 4; ++r)
          s += __expf(acc[mi][ni][r] + bias - m);
    }
#pragma unroll
    for (int d = 16; d <= 32; d <<= 1) {
      const float om = __shfl_xor(m, d);
      const float os = __shfl_xor(s, d);
      const float nm = fmaxf(m, om);
      s = s * __expf(m - nm) + os * __expf(om - nm);
      m = nm;
    }
    pm[ni] = m;
    psum[ni] = s;
  }
  __syncthreads();
  if (lg == 0) {
#pragma unroll
    for (int ni = 0; ni < 4; ++ni)
      sstat[wm][wn][ni][lr] = make_float2(pm[ni], psum[ni]);
  }
  __syncthreads();
  if (wm == 0 && lg == 0) {
#pragma unroll
    for (int ni = 0; ni < 4; ++ni) {
      const int v = n0 + wn * 64 + ni * 16 + lr;
      if (v < V_) {
        const float2 s0 = sstat[0][wn][ni][lr];
        const float2 s1 = sstat[1][wn][ni][lr];
        const float nm = fmaxf(s0.x, s1.x);
        const float ss =
            s0.y * __expf(s0.x - nm) + s1.y * __expf(s1.x - nm);
        pstats[(size_t)blockIdx.x * V_ + v] = make_float2(nm, ss);
      }
    }
  }
}

// ---------------------------------------------------------------------------
// K4a (merge): stats[b,v] = merge of 4 m-block partials.
// ---------------------------------------------------------------------------
__global__ __launch_bounds__(256) void k4_merge(const float2* __restrict__ pstats,
                                                float* __restrict__ stats) {
  const int gg = blockIdx.x * 256 + threadIdx.x;  // b*V + v, exact grid
  const int b = gg / V_;
  const int v = gg - b * V_;
  float m = -3.4e38f, s = 0.f;
#pragma unroll
  for (int i = 0; i < 4; ++i) {
    const float2 p = pstats[(size_t)(4 * b + i) * V_ + v];
    const float nm = fmaxf(m, p.x);
    s = s * __expf(m - nm) + p.y * __expf(p.x - nm);
    m = nm;
  }
  stats[2 * gg] = m;
  stats[2 * gg + 1] = 1.f / s;
}

// ---------------------------------------------------------------------------
// K4b: normalize, 8 floats/thread (2x float4), no int-div (banked r16).
// ---------------------------------------------------------------------------
__global__ __launch_bounds__(256) void k4_norm(float* __restrict__ logits,
                                               const float* __restrict__ stats) {
  const int bs = blockIdx.y;
  const int b = bs >> 9;
  const int v0 = blockIdx.x * 2048 + threadIdx.x * 8;
  if (v0 >= V_) return;
  float* p = logits + (size_t)bs * V_ + v0;
  const float* st = stats + 2 * (b * V_ + v0);
  const float4 l0 = *(const float4*)&p[0];
  const float4 l1 = *(const float4*)&p[4];
  const float4 s0 = *(const float4*)&st[0];
  const float4 s1 = *(const float4*)&st[4];
  const float4 s2 = *(const float4*)&st[8];
  const float4 s3 = *(const float4*)&st[12];
  float4 o0, o1;
  o0.x = __expf(l0.x - s0.x) * s0.y;
  o0.y = __expf(l0.y - s0.z) * s0.w;
  o0.z = __expf(l0.z - s1.x) * s1.y;
  o0.w = __expf(l0.w - s1.z) * s1.w;
  o1.x = __expf(l1.x - s2.x) * s2.y;
  o1.y = __expf(l1.y - s2.z) * s2.w;
  o1.z = __expf(l1.z - s3.x) * s3.y;
  o1.w = __expf(l1.w - s3.z) * s3.w;
  *(float4*)&p[0] = o0;
  *(float4*)&p[4] = o1;
}

extern "C" void kernel_launch(void* const* d_in, const int* in_sizes, int n_in,
                              void* d_out, int out_size, void* d_ws,
                              size_t ws_size, hipStream_t stream) {
  const float* x    = (const float*)d_in[0];
  const float* W_ih = (const float*)d_in[1];
  const float* W_hh = (const float*)d_in[2];
  const float* b_ih = (const float*)d_in[3];
  const float* b_hh = (const float*)d_in[4];
  const float* W_fc = (const float*)d_in[5];
  const float* b_fc = (const float*)d_in[6];
  float* out = (float*)d_out;

  // ws layout (floats): xw | hs | stats | wfc_hi | wfc_lo | pstats
  //   part (256 KB, scan-only) ALIASES wfc_hi (k2 done before k5_wfc)
  //   hs_hi/hs_lo (bf16) ALIAS xw (dead after k2)
  float* ws = (float*)d_ws;
  float* xw    = ws;
  float* hs    = xw + (size_t)BS_ * H_;
  float* stats = hs + (size_t)BS_ * H_;
  unsigned short* wfc_hi = (unsigned short*)(stats + (size_t)2 * B_ * V_);
  unsigned short* wfc_lo = wfc_hi + (size_t)V_ * H_;
  float2* pstats = (float2*)(wfc_lo + (size_t)V_ * H_);  // 64*V float2
  u64* part = (u64*)wfc_hi;
  unsigned short* hs_hi = (unsigned short*)xw;
  unsigned short* hs_lo = hs_hi + (size_t)BS_ * H_;

  k0_init<<<PART_WORDS / 256, 256, 0, stream>>>(part);
  k1_xw<<<dim3(BS_ / 64, H_ / 64), 256, 0, stream>>>(x, W_ih, b_ih, b_hh, xw);
  k2_scan<<<NBLK, 576, 0, stream>>>(xw, W_hh, hs, part);
  k5_split<<<((V_ * H_ / 4) + 255) / 256, 256, 0, stream>>>(W_fc, wfc_hi,
                                                            wfc_lo, V_ * H_ / 4);
  k5_split<<<((BS_ * H_ / 4) + 255) / 256, 256, 0, stream>>>(
      hs, hs_hi, hs_lo, BS_ * H_ / 4);
  k3_logits<<<dim3(BS_ / 128, (V_ + 127) / 128), 256, 0, stream>>>(
      hs_hi, hs_lo, wfc_hi, wfc_lo, b_fc, out, pstats);
  k4_merge<<<(B_ * V_) / 256, 256, 0, stream>>>(pstats, stats);
  k4_norm<<<dim3((V_ + 2047) / 2048, BS_), 256, 0, stream>>>(out, stats);
}

// Round 18
// 1234.501 us; speedup vs baseline: 1.2256x; 1.0440x over previous
//
#include <hip/hip_runtime.h>
#include <hip/hip_bf16.h>
#include <math.h>

#define B_ 16
#define S_ 512
#define E_ 300
#define H_ 512
#define V_ 10000
#define BS_ (B_ * S_)  // 8192

#define NSL 16           // slices (blocks) per batch, j-split
#define JPB (H_ / NSL)   // 32 output rows per block
#define NBLK (B_ * NSL)  // 256 blocks in the scan

typedef __attribute__((ext_vector_type(4))) float f32x4;
typedef __attribute__((ext_vector_type(8))) short bf16x8;
typedef unsigned long long u64;

// part region: fast[2][B][H] | safe[2][B][H]
#define PART_WORDS (4 * B_ * H_)

// ---------------------------------------------------------------------------
// K0: invalidate exchange tags in BOTH mailboxes.
// ---------------------------------------------------------------------------
__global__ __launch_bounds__(256) void k0_init(u64* __restrict__ part) {
  const int idx = blockIdx.x * 256 + threadIdx.x;
  part[idx] = 0xFFFFFFFF00000000ull;
}

// ---------------------------------------------------------------------------
// K1: xw = x @ W_ih^T + biases. 64x64 register-blocked (banked r16).
// ---------------------------------------------------------------------------
__global__ __launch_bounds__(256) void k1_xw(const float* __restrict__ x,
                                             const float* __restrict__ W_ih,
                                             const float* __restrict__ b_ih,
                                             const float* __restrict__ b_hh,
                                             float* __restrict__ xw) {
  __shared__ float As[64][156];
  __shared__ float Ws[64][156];
  const int row0 = blockIdx.x * 64;
  const int col0 = blockIdx.y * 64;
  const int tid = threadIdx.x;
  const int ty = tid >> 4, tx = tid & 15;
  float acc[4][4];
#pragma unroll
  for (int ii = 0; ii < 4; ++ii)
#pragma unroll
    for (int jj = 0; jj < 4; ++jj) acc[ii][jj] = 0.f;

  for (int idx = tid; idx < 64 * 38; idx += 256) {
    const int r = idx / 38, e4 = idx - r * 38;
    *(float4*)&As[r][e4 * 4] =
        *(const float4*)&x[(size_t)(row0 + r) * E_ + e4 * 4];
    *(float4*)&Ws[r][e4 * 4] =
        *(const float4*)&W_ih[(size_t)(col0 + r) * E_ + e4 * 4];
  }
  __syncthreads();
#pragma unroll 2
  for (int e4 = 0; e4 < 38; ++e4) {
    f32x4 a[4], w[4];
#pragma unroll
    for (int ii = 0; ii < 4; ++ii)
      a[ii] = *(const f32x4*)&As[ty + 16 * ii][e4 * 4];
#pragma unroll
    for (int jj = 0; jj < 4; ++jj)
      w[jj] = *(const f32x4*)&Ws[tx + 16 * jj][e4 * 4];
#pragma unroll
    for (int ii = 0; ii < 4; ++ii)
#pragma unroll
      for (int jj = 0; jj < 4; ++jj) {
        const f32x4 p = a[ii] * w[jj];
        acc[ii][jj] += p.x + p.y + p.z + p.w;
      }
  }
  __syncthreads();

  for (int idx = tid; idx < 64 * 37; idx += 256) {
    const int r = idx / 37, e4 = idx - r * 37;
    *(float4*)&As[r][e4 * 4] =
        *(const float4*)&x[(size_t)(row0 + r) * E_ + 152 + e4 * 4];
    *(float4*)&Ws[r][e4 * 4] =
        *(const float4*)&W_ih[(size_t)(col0 + r) * E_ + 152 + e4 * 4];
  }
  __syncthreads();
#pragma unroll 2
  for (int e4 = 0; e4 < 37; ++e4) {
    f32x4 a[4], w[4];
#pragma unroll
    for (int ii = 0; ii < 4; ++ii)
      a[ii] = *(const f32x4*)&As[ty + 16 * ii][e4 * 4];
#pragma unroll
    for (int jj = 0; jj < 4; ++jj)
      w[jj] = *(const f32x4*)&Ws[tx + 16 * jj][e4 * 4];
#pragma unroll
    for (int ii = 0; ii < 4; ++ii)
#pragma unroll
      for (int jj = 0; jj < 4; ++jj) {
        const f32x4 p = a[ii] * w[jj];
        acc[ii][jj] += p.x + p.y + p.z + p.w;
      }
  }

#pragma unroll
  for (int jj = 0; jj < 4; ++jj) {
    const int h = col0 + tx + 16 * jj;
    const float bb = b_ih[h] + b_hh[h];
#pragma unroll
    for (int ii = 0; ii < 4; ++ii)
      xw[(size_t)(row0 + ty + 16 * ii) * H_ + h] = acc[ii][jj] + bb;
  }
}

// sc1 (MALL-coherent) relaxed atomic load — always-correct path
__device__ __forceinline__ u64 pload(const u64* p) {
  return __hip_atomic_load(p, __ATOMIC_RELAXED, __HIP_MEMORY_SCOPE_AGENT);
}
// sc0 (L1-bypass, L2-point) load/store — fast path within one XCD
__device__ __forceinline__ u64 load_sc0(const u64* p) {
  u64 r;
  asm volatile("global_load_dwordx2 %0, %1, off sc0\n\ts_waitcnt vmcnt(0)"
               : "=v"(r) : "v"(p) : "memory");
  return r;
}
__device__ __forceinline__ void store_sc0(u64* p, u64 v) {
  asm volatile("global_store_dwordx2 %0, %1, off sc0" :: "v"(p), "v"(v)
               : "memory");
}

// ---------------------------------------------------------------------------
// K2: scan — ROUND-12 VERBATIM (banked: 692-702 us across r12/r13/r15/r16,
// FETCH 28.7 MB, conflicts 0). Failed deviations: r9 dual-batch (1650),
// r10 unbounded fast spin (hang), r11 deferred sc1 publish (1970), r14
// wave-specialized publisher (878), r17 insurance wave (708-733, FETCH up).
// k2 is at its empirical structural floor. DO NOT MODIFY.
// ---------------------------------------------------------------------------
__global__ __launch_bounds__(512) void k2_scan(
    const float* __restrict__ xw, const float* __restrict__ W_hh,
    float* __restrict__ hs, u64* __restrict__ part) {
  const int b = blockIdx.x & 15;  // batch -> XCD b%8 under round-robin
  const int g = blockIdx.x >> 4;  // slice
  const int tid = threadIdx.x;
  const int j = tid >> 4;         // 0..31 row within slice
  const int q = tid & 15;         // k-sixteenth
  const int jg = g * JPB + j;     // global output row

  __shared__ f32x4 Wp[8 * 512];   // 64 KB, instruction-major W
  __shared__ f32x4 hp4[2][128];   // 4 KB, double-buffered h (i4-major)

  {
    const float* wrow = &W_hh[(size_t)jg * H_ + q * 32];
#pragma unroll
    for (int i4 = 0; i4 < 8; ++i4)
      Wp[i4 * 512 + tid] = *(const f32x4*)&wrow[i4 * 4];
  }
  if (tid < 128) hp4[0][tid] = (f32x4)0.f;

  u64* const pf = part + (size_t)b * H_;             // +slot*B*H
  u64* const ps = part + (size_t)(2 * B_ + b) * H_;  // +slot*B*H
  const int kk = ((tid & 63) >> 2) * 32 + (tid >> 6) * 4 + (tid & 3);
  bool fast = true;

  float xwv = xw[(size_t)b * S_ * H_ + jg];  // t = 0
  __syncthreads();

  for (int t = 0; t < S_; ++t) {
    const int cur = t & 1;
    f32x4 a4 = (f32x4)0.f;
#pragma unroll
    for (int i4 = 0; i4 < 8; ++i4) {
      const f32x4 wv = Wp[i4 * 512 + tid];
      const f32x4 hv = hp4[cur][i4 * 16 + q];
      a4 += wv * hv;
    }
    float acc = a4.x + a4.y + a4.z + a4.w;
    acc += __shfl_xor(acc, 1);
    acc += __shfl_xor(acc, 2);
    acc += __shfl_xor(acc, 4);
    acc += __shfl_xor(acc, 8);

    if (q == 0) {
      const float hn = tanhf(xwv + acc);
      const u64 pk =
          ((u64)(unsigned)t << 32) | (u64)(unsigned)__float_as_uint(hn);
      store_sc0(&pf[(size_t)cur * (B_ * H_) + jg], pk);
      __hip_atomic_store(&ps[(size_t)cur * (B_ * H_) + jg], pk,
                         __ATOMIC_RELAXED, __HIP_MEMORY_SCOPE_AGENT);
      hs[((size_t)b * S_ + t) * H_ + jg] = hn;
    }
    const int tn = (t + 1 < S_) ? t + 1 : t;
    const float xw_next = xw[((size_t)b * S_ + tn) * H_ + jg];

    if (t + 1 < S_) {
      u64 v = 0;
      bool got = false;
      const u64* fw = &pf[(size_t)cur * (B_ * H_) + kk];
      if (fast) {
        for (int it = 0; it < 64; ++it) {
          v = load_sc0(fw);
          if ((unsigned)(v >> 32) == (unsigned)t) { got = true; break; }
        }
        if (!got) fast = false;  // sticky downgrade (cross-XCD placement)
      }
      if (!got) {
        const u64* sw = &ps[(size_t)cur * (B_ * H_) + kk];
        v = pload(sw);
        while ((unsigned)(v >> 32) != (unsigned)t) v = pload(sw);
      }
      ((float*)&hp4[cur ^ 1][0])[tid] = __uint_as_float((unsigned)v);
    }
    xwv = xw_next;
    __syncthreads();
  }
}

// ---------------------------------------------------------------------------
// K5a: split f32 -> bf16 hi + bf16 lo (RTN both; lo = f - hi). For W_fc.
// ---------------------------------------------------------------------------
__device__ __forceinline__ unsigned short bf16_rtn(float f) {
  unsigned u = __float_as_uint(f);
  return (unsigned short)((u + 0x7FFFu + ((u >> 16) & 1u)) >> 16);
}
__global__ __launch_bounds__(256) void k5_split(const float* __restrict__ src,
                                                unsigned short* __restrict__ hi,
                                                unsigned short* __restrict__ lo,
                                                int n4) {
  const int i = blockIdx.x * 256 + threadIdx.x;
  if (i >= n4) return;
  const float4 f = *(const float4*)&src[i * 4];
  unsigned short h[4], l[4];
  const float ff[4] = {f.x, f.y, f.z, f.w};
#pragma unroll
  for (int k = 0; k < 4; ++k) {
    h[k] = bf16_rtn(ff[k]);
    const float fh = __uint_as_float((unsigned)h[k] << 16);
    l[k] = bf16_rtn(ff[k] - fh);
  }
  *(ushort4*)&hi[i * 4] = make_ushort4(h[0], h[1], h[2], h[3]);
  *(ushort4*)&lo[i * 4] = make_ushort4(l[0], l[1], l[2], l[3]);
}

// ---------------------------------------------------------------------------
// K5b: plain f32 -> bf16 RTN cast (for hs; r18 2-product experiment).
// ---------------------------------------------------------------------------
__global__ __launch_bounds__(256) void k5_cast(const float* __restrict__ src,
                                               unsigned short* __restrict__ dst,
                                               int n4) {
  const int i = blockIdx.x * 256 + threadIdx.x;
  if (i >= n4) return;
  const float4 f = *(const float4*)&src[i * 4];
  *(ushort4*)&dst[i * 4] = make_ushort4(bf16_rtn(f.x), bf16_rtn(f.y),
                                        bf16_rtn(f.z), bf16_rtn(f.w));
}

// ---------------------------------------------------------------------------
// K3: logits = hs_bf16 @ (W_hi + W_lo)^T + b_fc  — r18 2-PRODUCT split
// (was 3-product hi/lo x hi/lo). Error budget: (h - h_bf16)·W ~ 1.1e-3 RMS
// logit -> Δp ~ 2-3e-4 (threshold 9.5e-4). Gains: MFMA 48->32/k-step,
// ds_read 16->12, LDS 66->49 KB => 3 blocks/CU (+50% TLP). Staging: 3
// arrays x 8 chunks = 24 gload_lds per k-step, 6 per wave, precomputed
// pointers (compile-time-indexed arrays -> registers, rule #20).
// 2-phase double-buffered + fused softmax partials (banked r13/r15).
// ---------------------------------------------------------------------------
__global__ __launch_bounds__(256) void k3_logits(
    const unsigned short* __restrict__ Abg, const unsigned short* __restrict__ Bhg,
    const unsigned short* __restrict__ Blg, const float* __restrict__ b_fc,
    float* __restrict__ out, float2* __restrict__ pstats) {
  __shared__ unsigned short Ab[2][128 * 32];
  __shared__ unsigned short Bh[2][128 * 32];
  __shared__ unsigned short Bl[2][128 * 32];
  __shared__ float2 sstat[2][2][4][16];  // [wm][wn][ni][lr]
  const int m0 = blockIdx.x * 128;
  const int n0 = blockIdx.y * 128;
  const int tid = threadIdx.x;
  const int lane = tid & 63;
  const int wave = tid >> 6;
  const int wm = wave >> 1, wn = wave & 1;
  const int lr = lane & 15;
  const int lg = lane >> 4;
  const int cxr = (lg ^ (lr & 3)) * 8;  // swizzled k-chunk (shorts)
  const int lrow = lane >> 2;
  const int lchunk = (lane & 3) ^ (lrow & 3);

  // staging assignment: flattened id = wave*6+t over {arr 0..2} x {c16 0..7}
  const unsigned short* src[6];
  unsigned short* d0[6];
  unsigned short* d1[6];
#pragma unroll
  for (int t = 0; t < 6; ++t) {
    const int id = wave * 6 + t;
    const int arr = id >> 3;  // 0:Ab 1:Bh 2:Bl (wave-uniform)
    const int c16 = id & 7;
    const int r = c16 * 16 + lrow;
    const int grow = (arr == 0) ? (m0 + r) : min(n0 + r, V_ - 1);
    const unsigned short* g = (arr == 0) ? Abg : (arr == 1) ? Bhg : Blg;
    src[t] = g + (size_t)grow * H_ + lchunk * 8;
    unsigned short* l0 = (arr == 0) ? Ab[0] : (arr == 1) ? Bh[0] : Bl[0];
    unsigned short* l1 = (arr == 0) ? Ab[1] : (arr == 1) ? Bh[1] : Bl[1];
    d0[t] = l0 + c16 * 512;
    d1[t] = l1 + c16 * 512;
  }

  f32x4 acc[4][4];
#pragma unroll
  for (int mi = 0; mi < 4; ++mi)
#pragma unroll
    for (int ni = 0; ni < 4; ++ni) acc[mi][ni] = (f32x4)0.0f;

  auto STAGE0 = [&](int k0) {
#pragma unroll
    for (int t = 0; t < 6; ++t)
      __builtin_amdgcn_global_load_lds(
          (const __attribute__((address_space(1))) void*)(src[t] + k0),
          (__attribute__((address_space(3))) void*)d0[t], 16, 0, 0);
  };
  auto STAGE1 = [&](int k0) {
#pragma unroll
    for (int t = 0; t < 6; ++t)
      __builtin_amdgcn_global_load_lds(
          (const __attribute__((address_space(1))) void*)(src[t] + k0),
          (__attribute__((address_space(3))) void*)d1[t], 16, 0, 0);
  };
  auto COMPUTE = [&](int buf) {
    bf16x8 ab[4], bh[4], bl[4];
#pragma unroll
    for (int i = 0; i < 4; ++i) {
      ab[i] = *(const bf16x8*)&Ab[buf][(wm * 64 + i * 16 + lr) * 32 + cxr];
      bh[i] = *(const bf16x8*)&Bh[buf][(wn * 64 + i * 16 + lr) * 32 + cxr];
      bl[i] = *(const bf16x8*)&Bl[buf][(wn * 64 + i * 16 + lr) * 32 + cxr];
    }
#pragma unroll
    for (int mi = 0; mi < 4; ++mi)
#pragma unroll
      for (int ni = 0; ni < 4; ++ni) {
        acc[mi][ni] = __builtin_amdgcn_mfma_f32_16x16x32_bf16(
            ab[mi], bh[ni], acc[mi][ni], 0, 0, 0);
        acc[mi][ni] = __builtin_amdgcn_mfma_f32_16x16x32_bf16(
            ab[mi], bl[ni], acc[mi][ni], 0, 0, 0);
      }
  };

  STAGE0(0);
  __syncthreads();
  for (int kt = 0; kt < 16; kt += 2) {
    STAGE1((kt + 1) * 32);
    COMPUTE(0);
    __syncthreads();
    if (kt + 2 < 16) STAGE0((kt + 2) * 32);
    COMPUTE(1);
    __syncthreads();
  }

  // C-write (logits + bias)
#pragma unroll
  for (int ni = 0; ni < 4; ++ni) {
    const int v = n0 + wn * 64 + ni * 16 + lr;
    if (v >= V_) continue;
    const float bias = b_fc[v];
#pragma unroll
    for (int mi = 0; mi < 4; ++mi) {
      const int mrow = m0 + wm * 64 + mi * 16 + lg * 4;
#pragma unroll
      for (int r = 0; r < 4; ++r)
        out[(size_t)(mrow + r) * V_ + v] = acc[mi][ni][r] + bias;
    }
  }

  // fused softmax partials over this block's 128 rows (one batch slice)
  float pm[4], psum[4];
#pragma unroll
  for (int ni = 0; ni < 4; ++ni) {
    const int v = n0 + wn * 64 + ni * 16 + lr;
    float m = -3.4e38f, s = 0.f;
    if (v < V_) {
      const float bias = b_fc[v];
#pragma unroll
      for (int mi = 0; mi < 4; ++mi)
#pragma unroll
        for (int r = 0; r < 4; ++r)
          m = fmaxf(m, acc[mi][ni][r] + bias);
#pragma unroll
      for (int mi = 0; mi < 4; ++mi)
#pragma unroll
        for (int r = 0; r < 4; ++r)
          s += __expf(acc[mi][ni][r] + bias - m);
    }
#pragma unroll
    for (int d = 16; d <= 32; d <<= 1) {
      const float om = __shfl_xor(m, d);
      const float os = __shfl_xor(s, d);
      const float nm = fmaxf(m, om);
      s = s * __expf(m - nm) + os * __expf(om - nm);
      m = nm;
    }
    pm[ni] = m;
    psum[ni] = s;
  }
  __syncthreads();
  if (lg == 0) {
#pragma unroll
    for (int ni = 0; ni < 4; ++ni)
      sstat[wm][wn][ni][lr] = make_float2(pm[ni], psum[ni]);
  }
  __syncthreads();
  if (wm == 0 && lg == 0) {
#pragma unroll
    for (int ni = 0; ni < 4; ++ni) {
      const int v = n0 + wn * 64 + ni * 16 + lr;
      if (v < V_) {
        const float2 s0 = sstat[0][wn][ni][lr];
        const float2 s1 = sstat[1][wn][ni][lr];
        const float nm = fmaxf(s0.x, s1.x);
        const float ss =
            s0.y * __expf(s0.x - nm) + s1.y * __expf(s1.x - nm);
        pstats[(size_t)blockIdx.x * V_ + v] = make_float2(nm, ss);
      }
    }
  }
}

// ---------------------------------------------------------------------------
// K4a (merge): stats[b,v] = merge of 4 m-block partials.
// ---------------------------------------------------------------------------
__global__ __launch_bounds__(256) void k4_merge(const float2* __restrict__ pstats,
                                                float* __restrict__ stats) {
  const int gg = blockIdx.x * 256 + threadIdx.x;  // b*V + v, exact grid
  const int b = gg / V_;
  const int v = gg - b * V_;
  float m = -3.4e38f, s = 0.f;
#pragma unroll
  for (int i = 0; i < 4; ++i) {
    const float2 p = pstats[(size_t)(4 * b + i) * V_ + v];
    const float nm = fmaxf(m, p.x);
    s = s * __expf(m - nm) + p.y * __expf(p.x - nm);
    m = nm;
  }
  stats[2 * gg] = m;
  stats[2 * gg + 1] = 1.f / s;
}

// ---------------------------------------------------------------------------
// K4b: normalize, 8 floats/thread (2x float4), no int-div (banked r16).
// ---------------------------------------------------------------------------
__global__ __launch_bounds__(256) void k4_norm(float* __restrict__ logits,
                                               const float* __restrict__ stats) {
  const int bs = blockIdx.y;
  const int b = bs >> 9;
  const int v0 = blockIdx.x * 2048 + threadIdx.x * 8;
  if (v0 >= V_) return;
  float* p = logits + (size_t)bs * V_ + v0;
  const float* st = stats + 2 * (b * V_ + v0);
  const float4 l0 = *(const float4*)&p[0];
  const float4 l1 = *(const float4*)&p[4];
  const float4 s0 = *(const float4*)&st[0];
  const float4 s1 = *(const float4*)&st[4];
  const float4 s2 = *(const float4*)&st[8];
  const float4 s3 = *(const float4*)&st[12];
  float4 o0, o1;
  o0.x = __expf(l0.x - s0.x) * s0.y;
  o0.y = __expf(l0.y - s0.z) * s0.w;
  o0.z = __expf(l0.z - s1.x) * s1.y;
  o0.w = __expf(l0.w - s1.z) * s1.w;
  o1.x = __expf(l1.x - s2.x) * s2.y;
  o1.y = __expf(l1.y - s2.z) * s2.w;
  o1.z = __expf(l1.z - s3.x) * s3.y;
  o1.w = __expf(l1.w - s3.z) * s3.w;
  *(float4*)&p[0] = o0;
  *(float4*)&p[4] = o1;
}

extern "C" void kernel_launch(void* const* d_in, const int* in_sizes, int n_in,
                              void* d_out, int out_size, void* d_ws,
                              size_t ws_size, hipStream_t stream) {
  const float* x    = (const float*)d_in[0];
  const float* W_ih = (const float*)d_in[1];
  const float* W_hh = (const float*)d_in[2];
  const float* b_ih = (const float*)d_in[3];
  const float* b_hh = (const float*)d_in[4];
  const float* W_fc = (const float*)d_in[5];
  const float* b_fc = (const float*)d_in[6];
  float* out = (float*)d_out;

  // ws layout (floats): xw | hs | stats | wfc_hi | wfc_lo | pstats
  //   part (256 KB, scan-only) ALIASES wfc_hi (k2 done before k5_split)
  //   hs_b (bf16) ALIASES xw (dead after k2)
  float* ws = (float*)d_ws;
  float* xw    = ws;
  float* hs    = xw + (size_t)BS_ * H_;
  float* stats = hs + (size_t)BS_ * H_;
  unsigned short* wfc_hi = (unsigned short*)(stats + (size_t)2 * B_ * V_);
  unsigned short* wfc_lo = wfc_hi + (size_t)V_ * H_;
  float2* pstats = (float2*)(wfc_lo + (size_t)V_ * H_);  // 64*V float2
  u64* part = (u64*)wfc_hi;
  unsigned short* hs_b = (unsigned short*)xw;

  k0_init<<<PART_WORDS / 256, 256, 0, stream>>>(part);
  k1_xw<<<dim3(BS_ / 64, H_ / 64), 256, 0, stream>>>(x, W_ih, b_ih, b_hh, xw);
  k2_scan<<<NBLK, 512, 0, stream>>>(xw, W_hh, hs, part);
  k5_split<<<((V_ * H_ / 4) + 255) / 256, 256, 0, stream>>>(W_fc, wfc_hi,
                                                            wfc_lo, V_ * H_ / 4);
  k5_cast<<<((BS_ * H_ / 4) + 255) / 256, 256, 0, stream>>>(hs, hs_b,
                                                            BS_ * H_ / 4);
  k3_logits<<<dim3(BS_ / 128, (V_ + 127) / 128), 256, 0, stream>>>(
      hs_b, wfc_hi, wfc_lo, b_fc, out, pstats);
  k4_merge<<<(B_ * V_) / 256, 256, 0, stream>>>(pstats, stats);
  k4_norm<<<dim3((V_ + 2047) / 2048, BS_), 256, 0, stream>>>(out, stats);
}

// Round 19
// 1103.741 us; speedup vs baseline: 1.3708x; 1.1185x over previous
//
#include <hip/hip_runtime.h>
#include <hip/hip_bf16.h>
#include <math.h>

#define B_ 16
#define S_ 512
#define E_ 300
#define H_ 512
#define V_ 10000
#define BS_ (B_ * S_)  // 8192

#define NSL 16           // slices (blocks) per batch, j-split
#define JPB (H_ / NSL)   // 32 output rows per block
#define NBLK (B_ * NSL)  // 256 blocks in the scan
#define NT ((V_ + 127) / 128)  // 79 n-tiles in k3

typedef __attribute__((ext_vector_type(4))) float f32x4;
typedef __attribute__((ext_vector_type(8))) short bf16x8;
typedef unsigned long long u64;

// part region: fast[2][B][H] | safe[2][B][H]
#define PART_WORDS (4 * B_ * H_)
// stat mailbox: [mblk=64][nt=79][col=128] u64 (m<<32 | s), NaN-init
#define STAT_WORDS (64 * NT * 128)

// ---------------------------------------------------------------------------
// K0: invalidate k2 exchange tags + k3 stat mailbox (NaN-pattern = "empty";
// logit maxima are finite so 0xFFC00000 upper word never occurs naturally).
// ---------------------------------------------------------------------------
__global__ __launch_bounds__(256) void k0_init(u64* __restrict__ part,
                                               u64* __restrict__ statmb) {
  const int idx = blockIdx.x * 256 + threadIdx.x;
  if (idx < PART_WORDS) part[idx] = 0xFFFFFFFF00000000ull;
  if (idx < STAT_WORDS) statmb[idx] = 0xFFC00000FFC00000ull;
}

// ---------------------------------------------------------------------------
// K1: xw = x @ W_ih^T + biases. 64x64 register-blocked (banked r16).
// ---------------------------------------------------------------------------
__global__ __launch_bounds__(256) void k1_xw(const float* __restrict__ x,
                                             const float* __restrict__ W_ih,
                                             const float* __restrict__ b_ih,
                                             const float* __restrict__ b_hh,
                                             float* __restrict__ xw) {
  __shared__ float As[64][156];
  __shared__ float Ws[64][156];
  const int row0 = blockIdx.x * 64;
  const int col0 = blockIdx.y * 64;
  const int tid = threadIdx.x;
  const int ty = tid >> 4, tx = tid & 15;
  float acc[4][4];
#pragma unroll
  for (int ii = 0; ii < 4; ++ii)
#pragma unroll
    for (int jj = 0; jj < 4; ++jj) acc[ii][jj] = 0.f;

  for (int idx = tid; idx < 64 * 38; idx += 256) {
    const int r = idx / 38, e4 = idx - r * 38;
    *(float4*)&As[r][e4 * 4] =
        *(const float4*)&x[(size_t)(row0 + r) * E_ + e4 * 4];
    *(float4*)&Ws[r][e4 * 4] =
        *(const float4*)&W_ih[(size_t)(col0 + r) * E_ + e4 * 4];
  }
  __syncthreads();
#pragma unroll 2
  for (int e4 = 0; e4 < 38; ++e4) {
    f32x4 a[4], w[4];
#pragma unroll
    for (int ii = 0; ii < 4; ++ii)
      a[ii] = *(const f32x4*)&As[ty + 16 * ii][e4 * 4];
#pragma unroll
    for (int jj = 0; jj < 4; ++jj)
      w[jj] = *(const f32x4*)&Ws[tx + 16 * jj][e4 * 4];
#pragma unroll
    for (int ii = 0; ii < 4; ++ii)
#pragma unroll
      for (int jj = 0; jj < 4; ++jj) {
        const f32x4 p = a[ii] * w[jj];
        acc[ii][jj] += p.x + p.y + p.z + p.w;
      }
  }
  __syncthreads();

  for (int idx = tid; idx < 64 * 37; idx += 256) {
    const int r = idx / 37, e4 = idx - r * 37;
    *(float4*)&As[r][e4 * 4] =
        *(const float4*)&x[(size_t)(row0 + r) * E_ + 152 + e4 * 4];
    *(float4*)&Ws[r][e4 * 4] =
        *(const float4*)&W_ih[(size_t)(col0 + r) * E_ + 152 + e4 * 4];
  }
  __syncthreads();
#pragma unroll 2
  for (int e4 = 0; e4 < 37; ++e4) {
    f32x4 a[4], w[4];
#pragma unroll
    for (int ii = 0; ii < 4; ++ii)
      a[ii] = *(const f32x4*)&As[ty + 16 * ii][e4 * 4];
#pragma unroll
    for (int jj = 0; jj < 4; ++jj)
      w[jj] = *(const f32x4*)&Ws[tx + 16 * jj][e4 * 4];
#pragma unroll
    for (int ii = 0; ii < 4; ++ii)
#pragma unroll
      for (int jj = 0; jj < 4; ++jj) {
        const f32x4 p = a[ii] * w[jj];
        acc[ii][jj] += p.x + p.y + p.z + p.w;
      }
  }

#pragma unroll
  for (int jj = 0; jj < 4; ++jj) {
    const int h = col0 + tx + 16 * jj;
    const float bb = b_ih[h] + b_hh[h];
#pragma unroll
    for (int ii = 0; ii < 4; ++ii)
      xw[(size_t)(row0 + ty + 16 * ii) * H_ + h] = acc[ii][jj] + bb;
  }
}

// sc1 (MALL-coherent) relaxed atomic load — always-correct path
__device__ __forceinline__ u64 pload(const u64* p) {
  return __hip_atomic_load(p, __ATOMIC_RELAXED, __HIP_MEMORY_SCOPE_AGENT);
}
// sc0 (L1-bypass, L2-point) load/store — fast path within one XCD
__device__ __forceinline__ u64 load_sc0(const u64* p) {
  u64 r;
  asm volatile("global_load_dwordx2 %0, %1, off sc0\n\ts_waitcnt vmcnt(0)"
               : "=v"(r) : "v"(p) : "memory");
  return r;
}
__device__ __forceinline__ void store_sc0(u64* p, u64 v) {
  asm volatile("global_store_dwordx2 %0, %1, off sc0" :: "v"(p), "v"(v)
               : "memory");
}

// ---------------------------------------------------------------------------
// K2: scan — ROUND-12 VERBATIM (banked: 692-703 us across r12-r18, FETCH
// 28.7 MB, conflicts 0). Failed deviations: r9 dual-batch (1650), r10
// unbounded fast spin (hang), r11 deferred sc1 publish (1970), r14
// wave-specialized publisher (878), r17 insurance wave (708-733).
// k2 is at its empirical structural floor. DO NOT MODIFY.
// ---------------------------------------------------------------------------
__global__ __launch_bounds__(512) void k2_scan(
    const float* __restrict__ xw, const float* __restrict__ W_hh,
    float* __restrict__ hs, u64* __restrict__ part) {
  const int b = blockIdx.x & 15;  // batch -> XCD b%8 under round-robin
  const int g = blockIdx.x >> 4;  // slice
  const int tid = threadIdx.x;
  const int j = tid >> 4;         // 0..31 row within slice
  const int q = tid & 15;         // k-sixteenth
  const int jg = g * JPB + j;     // global output row

  __shared__ f32x4 Wp[8 * 512];   // 64 KB, instruction-major W
  __shared__ f32x4 hp4[2][128];   // 4 KB, double-buffered h (i4-major)

  {
    const float* wrow = &W_hh[(size_t)jg * H_ + q * 32];
#pragma unroll
    for (int i4 = 0; i4 < 8; ++i4)
      Wp[i4 * 512 + tid] = *(const f32x4*)&wrow[i4 * 4];
  }
  if (tid < 128) hp4[0][tid] = (f32x4)0.f;

  u64* const pf = part + (size_t)b * H_;             // +slot*B*H
  u64* const ps = part + (size_t)(2 * B_ + b) * H_;  // +slot*B*H
  const int kk = ((tid & 63) >> 2) * 32 + (tid >> 6) * 4 + (tid & 3);
  bool fast = true;

  float xwv = xw[(size_t)b * S_ * H_ + jg];  // t = 0
  __syncthreads();

  for (int t = 0; t < S_; ++t) {
    const int cur = t & 1;
    f32x4 a4 = (f32x4)0.f;
#pragma unroll
    for (int i4 = 0; i4 < 8; ++i4) {
      const f32x4 wv = Wp[i4 * 512 + tid];
      const f32x4 hv = hp4[cur][i4 * 16 + q];
      a4 += wv * hv;
    }
    float acc = a4.x + a4.y + a4.z + a4.w;
    acc += __shfl_xor(acc, 1);
    acc += __shfl_xor(acc, 2);
    acc += __shfl_xor(acc, 4);
    acc += __shfl_xor(acc, 8);

    if (q == 0) {
      const float hn = tanhf(xwv + acc);
      const u64 pk =
          ((u64)(unsigned)t << 32) | (u64)(unsigned)__float_as_uint(hn);
      store_sc0(&pf[(size_t)cur * (B_ * H_) + jg], pk);
      __hip_atomic_store(&ps[(size_t)cur * (B_ * H_) + jg], pk,
                         __ATOMIC_RELAXED, __HIP_MEMORY_SCOPE_AGENT);
      hs[((size_t)b * S_ + t) * H_ + jg] = hn;
    }
    const int tn = (t + 1 < S_) ? t + 1 : t;
    const float xw_next = xw[((size_t)b * S_ + tn) * H_ + jg];

    if (t + 1 < S_) {
      u64 v = 0;
      bool got = false;
      const u64* fw = &pf[(size_t)cur * (B_ * H_) + kk];
      if (fast) {
        for (int it = 0; it < 64; ++it) {
          v = load_sc0(fw);
          if ((unsigned)(v >> 32) == (unsigned)t) { got = true; break; }
        }
        if (!got) fast = false;  // sticky downgrade (cross-XCD placement)
      }
      if (!got) {
        const u64* sw = &ps[(size_t)cur * (B_ * H_) + kk];
        v = pload(sw);
        while ((unsigned)(v >> 32) != (unsigned)t) v = pload(sw);
      }
      ((float*)&hp4[cur ^ 1][0])[tid] = __uint_as_float((unsigned)v);
    }
    xwv = xw_next;
    __syncthreads();
  }
}

// ---------------------------------------------------------------------------
// K5a: split f32 -> bf16 hi + bf16 lo (RTN both; lo = f - hi). For W_fc.
// ---------------------------------------------------------------------------
__device__ __forceinline__ unsigned short bf16_rtn(float f) {
  unsigned u = __float_as_uint(f);
  return (unsigned short)((u + 0x7FFFu + ((u >> 16) & 1u)) >> 16);
}
__global__ __launch_bounds__(256) void k5_split(const float* __restrict__ src,
                                                unsigned short* __restrict__ hi,
                                                unsigned short* __restrict__ lo,
                                                int n4) {
  const int i = blockIdx.x * 256 + threadIdx.x;
  if (i >= n4) return;
  const float4 f = *(const float4*)&src[i * 4];
  unsigned short h[4], l[4];
  const float ff[4] = {f.x, f.y, f.z, f.w};
#pragma unroll
  for (int k = 0; k < 4; ++k) {
    h[k] = bf16_rtn(ff[k]);
    const float fh = __uint_as_float((unsigned)h[k] << 16);
    l[k] = bf16_rtn(ff[k] - fh);
  }
  *(ushort4*)&hi[i * 4] = make_ushort4(h[0], h[1], h[2], h[3]);
  *(ushort4*)&lo[i * 4] = make_ushort4(l[0], l[1], l[2], l[3]);
}

// ---------------------------------------------------------------------------
// K5b: plain f32 -> bf16 RTN cast (for hs; banked r18 2-product).
// ---------------------------------------------------------------------------
__global__ __launch_bounds__(256) void k5_cast(const float* __restrict__ src,
                                               unsigned short* __restrict__ dst,
                                               int n4) {
  const int i = blockIdx.x * 256 + threadIdx.x;
  if (i >= n4) return;
  const float4 f = *(const float4*)&src[i * 4];
  *(ushort4*)&dst[i * 4] = make_ushort4(bf16_rtn(f.x), bf16_rtn(f.y),
                                        bf16_rtn(f.z), bf16_rtn(f.w));
}

// ---------------------------------------------------------------------------
// K3: FULLY FUSED logits + softmax (r19). 2-product bf16 MFMA (banked r18)
// computes the 128x128 logit tile in registers; per-column (max, sum-exp)
// partials are exchanged among the 4 m-blocks of the same batch x n-tile
// through a tagged-u64 relaxed-agent mailbox (k2's proven primitive; NaN-
// pattern init = "empty", logit maxima are always finite); each block then
// writes FINAL probabilities exp(l-M)/S directly — eliminating k4_merge +
// k4_norm (654 MB of logit re-traffic).
// Deadlock-free: all 4 columns published strictly BEFORE any poll; partner
// blocks are dispatch-adjacent (consecutive blockIdx.x), so only the ~3
// residency-frontier blocks ever wait on unlaunched partners, and
// completing groups free CUs -> inductive progress. Spin is on the
// always-delivered sc1 channel (r10 rule).
// ---------------------------------------------------------------------------
__global__ __launch_bounds__(256) void k3_logits(
    const unsigned short* __restrict__ Abg, const unsigned short* __restrict__ Bhg,
    const unsigned short* __restrict__ Blg, const float* __restrict__ b_fc,
    float* __restrict__ out, u64* __restrict__ statmb) {
  __shared__ unsigned short Ab[2][128 * 32];
  __shared__ unsigned short Bh[2][128 * 32];
  __shared__ unsigned short Bl[2][128 * 32];
  __shared__ float2 sstat[2][2][4][16];  // [wm][wn][ni][lr]
  __shared__ float2 fstat[128];          // final (M, 1/S) per column
  const int m0 = blockIdx.x * 128;
  const int n0 = blockIdx.y * 128;
  const int tid = threadIdx.x;
  const int lane = tid & 63;
  const int wave = tid >> 6;
  const int wm = wave >> 1, wn = wave & 1;
  const int lr = lane & 15;
  const int lg = lane >> 4;
  const int cxr = (lg ^ (lr & 3)) * 8;  // swizzled k-chunk (shorts)
  const int lrow = lane >> 2;
  const int lchunk = (lane & 3) ^ (lrow & 3);

  // staging assignment: flattened id = wave*6+t over {arr 0..2} x {c16 0..7}
  const unsigned short* src[6];
  unsigned short* d0[6];
  unsigned short* d1[6];
#pragma unroll
  for (int t = 0; t < 6; ++t) {
    const int id = wave * 6 + t;
    const int arr = id >> 3;  // 0:Ab 1:Bh 2:Bl (wave-uniform)
    const int c16 = id & 7;
    const int r = c16 * 16 + lrow;
    const int grow = (arr == 0) ? (m0 + r) : min(n0 + r, V_ - 1);
    const unsigned short* g = (arr == 0) ? Abg : (arr == 1) ? Bhg : Blg;
    src[t] = g + (size_t)grow * H_ + lchunk * 8;
    unsigned short* l0 = (arr == 0) ? Ab[0] : (arr == 1) ? Bh[0] : Bl[0];
    unsigned short* l1 = (arr == 0) ? Ab[1] : (arr == 1) ? Bh[1] : Bl[1];
    d0[t] = l0 + c16 * 512;
    d1[t] = l1 + c16 * 512;
  }

  f32x4 acc[4][4];
#pragma unroll
  for (int mi = 0; mi < 4; ++mi)
#pragma unroll
    for (int ni = 0; ni < 4; ++ni) acc[mi][ni] = (f32x4)0.0f;

  auto STAGE0 = [&](int k0) {
#pragma unroll
    for (int t = 0; t < 6; ++t)
      __builtin_amdgcn_global_load_lds(
          (const __attribute__((address_space(1))) void*)(src[t] + k0),
          (__attribute__((address_space(3))) void*)d0[t], 16, 0, 0);
  };
  auto STAGE1 = [&](int k0) {
#pragma unroll
    for (int t = 0; t < 6; ++t)
      __builtin_amdgcn_global_load_lds(
          (const __attribute__((address_space(1))) void*)(src[t] + k0),
          (__attribute__((address_space(3))) void*)d1[t], 16, 0, 0);
  };
  auto COMPUTE = [&](int buf) {
    bf16x8 ab[4], bh[4], bl[4];
#pragma unroll
    for (int i = 0; i < 4; ++i) {
      ab[i] = *(const bf16x8*)&Ab[buf][(wm * 64 + i * 16 + lr) * 32 + cxr];
      bh[i] = *(const bf16x8*)&Bh[buf][(wn * 64 + i * 16 + lr) * 32 + cxr];
      bl[i] = *(const bf16x8*)&Bl[buf][(wn * 64 + i * 16 + lr) * 32 + cxr];
    }
#pragma unroll
    for (int mi = 0; mi < 4; ++mi)
#pragma unroll
      for (int ni = 0; ni < 4; ++ni) {
        acc[mi][ni] = __builtin_amdgcn_mfma_f32_16x16x32_bf16(
            ab[mi], bh[ni], acc[mi][ni], 0, 0, 0);
        acc[mi][ni] = __builtin_amdgcn_mfma_f32_16x16x32_bf16(
            ab[mi], bl[ni], acc[mi][ni], 0, 0, 0);
      }
  };

  STAGE0(0);
  __syncthreads();
  for (int kt = 0; kt < 16; kt += 2) {
    STAGE1((kt + 1) * 32);
    COMPUTE(0);
    __syncthreads();
    if (kt + 2 < 16) STAGE0((kt + 2) * 32);
    COMPUTE(1);
    __syncthreads();
  }

  // ---- per-block softmax partials (banked r13 structure) ----
  float pm[4], psum[4];
#pragma unroll
  for (int ni = 0; ni < 4; ++ni) {
    const int v = n0 + wn * 64 + ni * 16 + lr;
    float m = -3.4e38f, s = 0.f;
    if (v < V_) {
      const float bias = b_fc[v];
#pragma unroll
      for (int mi = 0; mi < 4; ++mi)
#pragma unroll
        for (int r = 0; r < 4; ++r)
          m = fmaxf(m, acc[mi][ni][r] + bias);
#pragma unroll
      for (int mi = 0; mi < 4; ++mi)
#pragma unroll
        for (int r = 0; r < 4; ++r)
          s += __expf(acc[mi][ni][r] + bias - m);
    }
#pragma unroll
    for (int d = 16; d <= 32; d <<= 1) {
      const float om = __shfl_xor(m, d);
      const float os = __shfl_xor(s, d);
      const float nm = fmaxf(m, om);
      s = s * __expf(m - nm) + os * __expf(om - nm);
      m = nm;
    }
    pm[ni] = m;
    psum[ni] = s;
  }
  __syncthreads();  // LDS tiles dead; sstat reuse safe
  if (lg == 0) {
#pragma unroll
    for (int ni = 0; ni < 4; ++ni)
      sstat[wm][wn][ni][lr] = make_float2(pm[ni], psum[ni]);
  }
  __syncthreads();

  // ---- cross-block exchange + finalize (waves 0-1, lanes lg==0) ----
  if (wave < 2 && lg == 0) {
    const int base = (int)(blockIdx.x & ~3u);  // 4 m-blocks of this batch
    float bm[4], bs[4];
    // merge wm-halves and PUBLISH all 4 columns first (deadlock-freedom)
#pragma unroll
    for (int ni = 0; ni < 4; ++ni) {
      const int col = wn * 64 + ni * 16 + lr;
      const float2 s0 = sstat[0][wn][ni][lr];
      const float2 s1 = sstat[1][wn][ni][lr];
      const float nm = fmaxf(s0.x, s1.x);
      bm[ni] = nm;
      bs[ni] = s0.y * __expf(s0.x - nm) + s1.y * __expf(s1.x - nm);
      const u64 pk = ((u64)(unsigned)__float_as_uint(bm[ni]) << 32) |
                     (u64)(unsigned)__float_as_uint(bs[ni]);
      __hip_atomic_store(
          &statmb[((size_t)blockIdx.x * NT + blockIdx.y) * 128 + col], pk,
          __ATOMIC_RELAXED, __HIP_MEMORY_SCOPE_AGENT);
    }
    // poll the 3 partners, merge, finalize
#pragma unroll
    for (int ni = 0; ni < 4; ++ni) {
      const int col = wn * 64 + ni * 16 + lr;
      float M = bm[ni], S = bs[ni];
      for (int i = 0; i < 4; ++i) {
        const int pb = base + i;
        if (pb == (int)blockIdx.x) continue;
        const u64* w = &statmb[((size_t)pb * NT + blockIdx.y) * 128 + col];
        u64 v = pload(w);
        while ((unsigned)(v >> 32) == 0xFFC00000u) v = pload(w);
        const float om = __uint_as_float((unsigned)(v >> 32));
        const float os = __uint_as_float((unsigned)v);
        const float nm = fmaxf(M, om);
        S = S * __expf(M - nm) + os * __expf(om - nm);
        M = nm;
      }
      fstat[col] = make_float2(M, 1.f / S);
    }
  }
  __syncthreads();

  // ---- final write: probabilities, straight from registers ----
#pragma unroll
  for (int ni = 0; ni < 4; ++ni) {
    const int v = n0 + wn * 64 + ni * 16 + lr;
    if (v >= V_) continue;
    const float bias = b_fc[v];
    const float2 fs = fstat[wn * 64 + ni * 16 + lr];
#pragma unroll
    for (int mi = 0; mi < 4; ++mi) {
      const int mrow = m0 + wm * 64 + mi * 16 + lg * 4;
#pragma unroll
      for (int r = 0; r < 4; ++r)
        out[(size_t)(mrow + r) * V_ + v] =
            __expf(acc[mi][ni][r] + bias - fs.x) * fs.y;
    }
  }
}

extern "C" void kernel_launch(void* const* d_in, const int* in_sizes, int n_in,
                              void* d_out, int out_size, void* d_ws,
                              size_t ws_size, hipStream_t stream) {
  const float* x    = (const float*)d_in[0];
  const float* W_ih = (const float*)d_in[1];
  const float* W_hh = (const float*)d_in[2];
  const float* b_ih = (const float*)d_in[3];
  const float* b_hh = (const float*)d_in[4];
  const float* W_fc = (const float*)d_in[5];
  const float* b_fc = (const float*)d_in[6];
  float* out = (float*)d_out;

  // ws layout: xw | hs | wfc_hi | wfc_lo | statmb  (59.2 MB)
  //   part (256 KB, scan-only) ALIASES wfc_hi (k2 done before k5_split)
  //   hs_b (bf16) ALIASES xw (dead after k2)
  float* ws = (float*)d_ws;
  float* xw    = ws;
  float* hs    = xw + (size_t)BS_ * H_;
  unsigned short* wfc_hi = (unsigned short*)(hs + (size_t)BS_ * H_);
  unsigned short* wfc_lo = wfc_hi + (size_t)V_ * H_;
  u64* statmb = (u64*)(wfc_lo + (size_t)V_ * H_);  // STAT_WORDS u64
  u64* part = (u64*)wfc_hi;
  unsigned short* hs_b = (unsigned short*)xw;

  k0_init<<<(STAT_WORDS + 255) / 256, 256, 0, stream>>>(part, statmb);
  k1_xw<<<dim3(BS_ / 64, H_ / 64), 256, 0, stream>>>(x, W_ih, b_ih, b_hh, xw);
  k2_scan<<<NBLK, 512, 0, stream>>>(xw, W_hh, hs, part);
  k5_split<<<((V_ * H_ / 4) + 255) / 256, 256, 0, stream>>>(W_fc, wfc_hi,
                                                            wfc_lo, V_ * H_ / 4);
  k5_cast<<<((BS_ * H_ / 4) + 255) / 256, 256, 0, stream>>>(hs, hs_b,
                                                            BS_ * H_ / 4);
  k3_logits<<<dim3(BS_ / 128, NT), 256, 0, stream>>>(hs_b, wfc_hi, wfc_lo,
                                                     b_fc, out, statmb);
}

// Round 20
// 1100.866 us; speedup vs baseline: 1.3744x; 1.0026x over previous
//
#include <hip/hip_runtime.h>
#include <hip/hip_bf16.h>
#include <math.h>

#define B_ 16
#define S_ 512
#define E_ 300
#define H_ 512
#define V_ 10000
#define BS_ (B_ * S_)  // 8192

#define NSL 16           // slices (blocks) per batch, j-split
#define JPB (H_ / NSL)   // 32 output rows per block
#define NBLK (B_ * NSL)  // 256 blocks in the scan
#define NT ((V_ + 127) / 128)  // 79 n-tiles in k3

typedef __attribute__((ext_vector_type(4))) float f32x4;
typedef __attribute__((ext_vector_type(8))) short bf16x8;
typedef unsigned long long u64;

// part region: fast[2][B][H] | safe[2][B][H]
#define PART_WORDS (4 * B_ * H_)
// stat mailbox: [mblk=64][nt=79][col=128] u64 (m<<32 | s), NaN-init
#define STAT_WORDS (64 * NT * 128)

// ---------------------------------------------------------------------------
// K0: invalidate k2 exchange tags + k3 stat mailbox (NaN-pattern = "empty").
// ---------------------------------------------------------------------------
__global__ __launch_bounds__(256) void k0_init(u64* __restrict__ part,
                                               u64* __restrict__ statmb) {
  const int idx = blockIdx.x * 256 + threadIdx.x;
  if (idx < PART_WORDS) part[idx] = 0xFFFFFFFF00000000ull;
  if (idx < STAT_WORDS) statmb[idx] = 0xFFC00000FFC00000ull;
}

// ---------------------------------------------------------------------------
// K1: xw = x @ W_ih^T + biases. 64x64 register-blocked (banked r16).
// ---------------------------------------------------------------------------
__global__ __launch_bounds__(256) void k1_xw(const float* __restrict__ x,
                                             const float* __restrict__ W_ih,
                                             const float* __restrict__ b_ih,
                                             const float* __restrict__ b_hh,
                                             float* __restrict__ xw) {
  __shared__ float As[64][156];
  __shared__ float Ws[64][156];
  const int row0 = blockIdx.x * 64;
  const int col0 = blockIdx.y * 64;
  const int tid = threadIdx.x;
  const int ty = tid >> 4, tx = tid & 15;
  float acc[4][4];
#pragma unroll
  for (int ii = 0; ii < 4; ++ii)
#pragma unroll
    for (int jj = 0; jj < 4; ++jj) acc[ii][jj] = 0.f;

  for (int idx = tid; idx < 64 * 38; idx += 256) {
    const int r = idx / 38, e4 = idx - r * 38;
    *(float4*)&As[r][e4 * 4] =
        *(const float4*)&x[(size_t)(row0 + r) * E_ + e4 * 4];
    *(float4*)&Ws[r][e4 * 4] =
        *(const float4*)&W_ih[(size_t)(col0 + r) * E_ + e4 * 4];
  }
  __syncthreads();
#pragma unroll 2
  for (int e4 = 0; e4 < 38; ++e4) {
    f32x4 a[4], w[4];
#pragma unroll
    for (int ii = 0; ii < 4; ++ii)
      a[ii] = *(const f32x4*)&As[ty + 16 * ii][e4 * 4];
#pragma unroll
    for (int jj = 0; jj < 4; ++jj)
      w[jj] = *(const f32x4*)&Ws[tx + 16 * jj][e4 * 4];
#pragma unroll
    for (int ii = 0; ii < 4; ++ii)
#pragma unroll
      for (int jj = 0; jj < 4; ++jj) {
        const f32x4 p = a[ii] * w[jj];
        acc[ii][jj] += p.x + p.y + p.z + p.w;
      }
  }
  __syncthreads();

  for (int idx = tid; idx < 64 * 37; idx += 256) {
    const int r = idx / 37, e4 = idx - r * 37;
    *(float4*)&As[r][e4 * 4] =
        *(const float4*)&x[(size_t)(row0 + r) * E_ + 152 + e4 * 4];
    *(float4*)&Ws[r][e4 * 4] =
        *(const float4*)&W_ih[(size_t)(col0 + r) * E_ + 152 + e4 * 4];
  }
  __syncthreads();
#pragma unroll 2
  for (int e4 = 0; e4 < 37; ++e4) {
    f32x4 a[4], w[4];
#pragma unroll
    for (int ii = 0; ii < 4; ++ii)
      a[ii] = *(const f32x4*)&As[ty + 16 * ii][e4 * 4];
#pragma unroll
    for (int jj = 0; jj < 4; ++jj)
      w[jj] = *(const f32x4*)&Ws[tx + 16 * jj][e4 * 4];
#pragma unroll
    for (int ii = 0; ii < 4; ++ii)
#pragma unroll
      for (int jj = 0; jj < 4; ++jj) {
        const f32x4 p = a[ii] * w[jj];
        acc[ii][jj] += p.x + p.y + p.z + p.w;
      }
  }

#pragma unroll
  for (int jj = 0; jj < 4; ++jj) {
    const int h = col0 + tx + 16 * jj;
    const float bb = b_ih[h] + b_hh[h];
#pragma unroll
    for (int ii = 0; ii < 4; ++ii)
      xw[(size_t)(row0 + ty + 16 * ii) * H_ + h] = acc[ii][jj] + bb;
  }
}

// sc1 (MALL-coherent) relaxed atomic load — always-correct path
__device__ __forceinline__ u64 pload(const u64* p) {
  return __hip_atomic_load(p, __ATOMIC_RELAXED, __HIP_MEMORY_SCOPE_AGENT);
}
// sc0 (L1-bypass, L2-point) load/store — fast path within one XCD
__device__ __forceinline__ u64 load_sc0(const u64* p) {
  u64 r;
  asm volatile("global_load_dwordx2 %0, %1, off sc0\n\ts_waitcnt vmcnt(0)"
               : "=v"(r) : "v"(p) : "memory");
  return r;
}
__device__ __forceinline__ void store_sc0(u64* p, u64 v) {
  asm volatile("global_store_dwordx2 %0, %1, off sc0" :: "v"(p), "v"(v)
               : "memory");
}

__device__ __forceinline__ unsigned short bf16_rtn(float f) {
  unsigned u = __float_as_uint(f);
  return (unsigned short)((u + 0x7FFFu + ((u >> 16) & 1u)) >> 16);
}

// ---------------------------------------------------------------------------
// K2: scan — r12 protocol VERBATIM (banked: 692-703 us across r12-r19,
// FETCH 28.7 MB, conflicts 0). r20's ONLY change: the fire-and-forget hs
// store writes bf16 directly (ushort) instead of f32 — k3 consumes only
// bf16, so this deletes k5_cast + 40 MB of cast traffic. NOT a protocol
// change (same publishes/polls/barriers). Fingerprint: WRITE_SIZE
// 49.3 -> ~41 MB. Failed protocol deviations (do not retry): r9 dual-batch,
// r10 unbounded spin (hang), r11 deferred sc1, r14 specialized publisher,
// r17 insurance wave.
// ---------------------------------------------------------------------------
__global__ __launch_bounds__(512) void k2_scan(
    const float* __restrict__ xw, const float* __restrict__ W_hh,
    unsigned short* __restrict__ hs_b, u64* __restrict__ part) {
  const int b = blockIdx.x & 15;  // batch -> XCD b%8 under round-robin
  const int g = blockIdx.x >> 4;  // slice
  const int tid = threadIdx.x;
  const int j = tid >> 4;         // 0..31 row within slice
  const int q = tid & 15;         // k-sixteenth
  const int jg = g * JPB + j;     // global output row

  __shared__ f32x4 Wp[8 * 512];   // 64 KB, instruction-major W
  __shared__ f32x4 hp4[2][128];   // 4 KB, double-buffered h (i4-major)

  {
    const float* wrow = &W_hh[(size_t)jg * H_ + q * 32];
#pragma unroll
    for (int i4 = 0; i4 < 8; ++i4)
      Wp[i4 * 512 + tid] = *(const f32x4*)&wrow[i4 * 4];
  }
  if (tid < 128) hp4[0][tid] = (f32x4)0.f;

  u64* const pf = part + (size_t)b * H_;             // +slot*B*H
  u64* const ps = part + (size_t)(2 * B_ + b) * H_;  // +slot*B*H
  const int kk = ((tid & 63) >> 2) * 32 + (tid >> 6) * 4 + (tid & 3);
  bool fast = true;

  float xwv = xw[(size_t)b * S_ * H_ + jg];  // t = 0
  __syncthreads();

  for (int t = 0; t < S_; ++t) {
    const int cur = t & 1;
    f32x4 a4 = (f32x4)0.f;
#pragma unroll
    for (int i4 = 0; i4 < 8; ++i4) {
      const f32x4 wv = Wp[i4 * 512 + tid];
      const f32x4 hv = hp4[cur][i4 * 16 + q];
      a4 += wv * hv;
    }
    float acc = a4.x + a4.y + a4.z + a4.w;
    acc += __shfl_xor(acc, 1);
    acc += __shfl_xor(acc, 2);
    acc += __shfl_xor(acc, 4);
    acc += __shfl_xor(acc, 8);

    if (q == 0) {
      const float hn = tanhf(xwv + acc);
      const u64 pk =
          ((u64)(unsigned)t << 32) | (u64)(unsigned)__float_as_uint(hn);
      store_sc0(&pf[(size_t)cur * (B_ * H_) + jg], pk);
      __hip_atomic_store(&ps[(size_t)cur * (B_ * H_) + jg], pk,
                         __ATOMIC_RELAXED, __HIP_MEMORY_SCOPE_AGENT);
      hs_b[((size_t)b * S_ + t) * H_ + jg] = bf16_rtn(hn);
    }
    const int tn = (t + 1 < S_) ? t + 1 : t;
    const float xw_next = xw[((size_t)b * S_ + tn) * H_ + jg];

    if (t + 1 < S_) {
      u64 v = 0;
      bool got = false;
      const u64* fw = &pf[(size_t)cur * (B_ * H_) + kk];
      if (fast) {
        for (int it = 0; it < 64; ++it) {
          v = load_sc0(fw);
          if ((unsigned)(v >> 32) == (unsigned)t) { got = true; break; }
        }
        if (!got) fast = false;  // sticky downgrade (cross-XCD placement)
      }
      if (!got) {
        const u64* sw = &ps[(size_t)cur * (B_ * H_) + kk];
        v = pload(sw);
        while ((unsigned)(v >> 32) != (unsigned)t) v = pload(sw);
      }
      ((float*)&hp4[cur ^ 1][0])[tid] = __uint_as_float((unsigned)v);
    }
    xwv = xw_next;
    __syncthreads();
  }
}

// ---------------------------------------------------------------------------
// K5: split f32 -> bf16 hi + bf16 lo (RTN both; lo = f - hi). For W_fc.
// ---------------------------------------------------------------------------
__global__ __launch_bounds__(256) void k5_split(const float* __restrict__ src,
                                                unsigned short* __restrict__ hi,
                                                unsigned short* __restrict__ lo,
                                                int n4) {
  const int i = blockIdx.x * 256 + threadIdx.x;
  if (i >= n4) return;
  const float4 f = *(const float4*)&src[i * 4];
  unsigned short h[4], l[4];
  const float ff[4] = {f.x, f.y, f.z, f.w};
#pragma unroll
  for (int k = 0; k < 4; ++k) {
    h[k] = bf16_rtn(ff[k]);
    const float fh = __uint_as_float((unsigned)h[k] << 16);
    l[k] = bf16_rtn(ff[k] - fh);
  }
  *(ushort4*)&hi[i * 4] = make_ushort4(h[0], h[1], h[2], h[3]);
  *(ushort4*)&lo[i * 4] = make_ushort4(l[0], l[1], l[2], l[3]);
}

// ---------------------------------------------------------------------------
// K3: FULLY FUSED logits + softmax (banked r19). 2-product bf16 MFMA,
// tagged-u64 cross-block stat exchange, final probabilities from registers.
// ---------------------------------------------------------------------------
__global__ __launch_bounds__(256) void k3_logits(
    const unsigned short* __restrict__ Abg, const unsigned short* __restrict__ Bhg,
    const unsigned short* __restrict__ Blg, const float* __restrict__ b_fc,
    float* __restrict__ out, u64* __restrict__ statmb) {
  __shared__ unsigned short Ab[2][128 * 32];
  __shared__ unsigned short Bh[2][128 * 32];
  __shared__ unsigned short Bl[2][128 * 32];
  __shared__ float2 sstat[2][2][4][16];  // [wm][wn][ni][lr]
  __shared__ float2 fstat[128];          // final (M, 1/S) per column
  const int m0 = blockIdx.x * 128;
  const int n0 = blockIdx.y * 128;
  const int tid = threadIdx.x;
  const int lane = tid & 63;
  const int wave = tid >> 6;
  const int wm = wave >> 1, wn = wave & 1;
  const int lr = lane & 15;
  const int lg = lane >> 4;
  const int cxr = (lg ^ (lr & 3)) * 8;  // swizzled k-chunk (shorts)
  const int lrow = lane >> 2;
  const int lchunk = (lane & 3) ^ (lrow & 3);

  const unsigned short* src[6];
  unsigned short* d0[6];
  unsigned short* d1[6];
#pragma unroll
  for (int t = 0; t < 6; ++t) {
    const int id = wave * 6 + t;
    const int arr = id >> 3;  // 0:Ab 1:Bh 2:Bl (wave-uniform)
    const int c16 = id & 7;
    const int r = c16 * 16 + lrow;
    const int grow = (arr == 0) ? (m0 + r) : min(n0 + r, V_ - 1);
    const unsigned short* g = (arr == 0) ? Abg : (arr == 1) ? Bhg : Blg;
    src[t] = g + (size_t)grow * H_ + lchunk * 8;
    unsigned short* l0 = (arr == 0) ? Ab[0] : (arr == 1) ? Bh[0] : Bl[0];
    unsigned short* l1 = (arr == 0) ? Ab[1] : (arr == 1) ? Bh[1] : Bl[1];
    d0[t] = l0 + c16 * 512;
    d1[t] = l1 + c16 * 512;
  }

  f32x4 acc[4][4];
#pragma unroll
  for (int mi = 0; mi < 4; ++mi)
#pragma unroll
    for (int ni = 0; ni < 4; ++ni) acc[mi][ni] = (f32x4)0.0f;

  auto STAGE0 = [&](int k0) {
#pragma unroll
    for (int t = 0; t < 6; ++t)
      __builtin_amdgcn_global_load_lds(
          (const __attribute__((address_space(1))) void*)(src[t] + k0),
          (__attribute__((address_space(3))) void*)d0[t], 16, 0, 0);
  };
  auto STAGE1 = [&](int k0) {
#pragma unroll
    for (int t = 0; t < 6; ++t)
      __builtin_amdgcn_global_load_lds(
          (const __attribute__((address_space(1))) void*)(src[t] + k0),
          (__attribute__((address_space(3))) void*)d1[t], 16, 0, 0);
  };
  auto COMPUTE = [&](int buf) {
    bf16x8 ab[4], bh[4], bl[4];
#pragma unroll
    for (int i = 0; i < 4; ++i) {
      ab[i] = *(const bf16x8*)&Ab[buf][(wm * 64 + i * 16 + lr) * 32 + cxr];
      bh[i] = *(const bf16x8*)&Bh[buf][(wn * 64 + i * 16 + lr) * 32 + cxr];
      bl[i] = *(const bf16x8*)&Bl[buf][(wn * 64 + i * 16 + lr) * 32 + cxr];
    }
#pragma unroll
    for (int mi = 0; mi < 4; ++mi)
#pragma unroll
      for (int ni = 0; ni < 4; ++ni) {
        acc[mi][ni] = __builtin_amdgcn_mfma_f32_16x16x32_bf16(
            ab[mi], bh[ni], acc[mi][ni], 0, 0, 0);
        acc[mi][ni] = __builtin_amdgcn_mfma_f32_16x16x32_bf16(
            ab[mi], bl[ni], acc[mi][ni], 0, 0, 0);
      }
  };

  STAGE0(0);
  __syncthreads();
  for (int kt = 0; kt < 16; kt += 2) {
    STAGE1((kt + 1) * 32);
    COMPUTE(0);
    __syncthreads();
    if (kt + 2 < 16) STAGE0((kt + 2) * 32);
    COMPUTE(1);
    __syncthreads();
  }

  // ---- per-block softmax partials ----
  float pm[4], psum[4];
#pragma unroll
  for (int ni = 0; ni < 4; ++ni) {
    const int v = n0 + wn * 64 + ni * 16 + lr;
    float m = -3.4e38f, s = 0.f;
    if (v < V_) {
      const float bias = b_fc[v];
#pragma unroll
      for (int mi = 0; mi < 4; ++mi)
#pragma unroll
        for (int r = 0; r < 4; ++r)
          m = fmaxf(m, acc[mi][ni][r] + bias);
#pragma unroll
      for (int mi = 0; mi < 4; ++mi)
#pragma unroll
        for (int r = 0; r < 4; ++r)
          s += __expf(acc[mi][ni][r] + bias - m);
    }
#pragma unroll
    for (int d = 16; d <= 32; d <<= 1) {
      const float om = __shfl_xor(m, d);
      const float os = __shfl_xor(s, d);
      const float nm = fmaxf(m, om);
      s = s * __expf(m - nm) + os * __expf(om - nm);
      m = nm;
    }
    pm[ni] = m;
    psum[ni] = s;
  }
  __syncthreads();
  if (lg == 0) {
#pragma unroll
    for (int ni = 0; ni < 4; ++ni)
      sstat[wm][wn][ni][lr] = make_float2(pm[ni], psum[ni]);
  }
  __syncthreads();

  // ---- cross-block exchange + finalize (waves 0-1, lanes lg==0) ----
  if (wave < 2 && lg == 0) {
    const int base = (int)(blockIdx.x & ~3u);
    float bm[4], bs[4];
#pragma unroll
    for (int ni = 0; ni < 4; ++ni) {
      const int col = wn * 64 + ni * 16 + lr;
      const float2 s0 = sstat[0][wn][ni][lr];
      const float2 s1 = sstat[1][wn][ni][lr];
      const float nm = fmaxf(s0.x, s1.x);
      bm[ni] = nm;
      bs[ni] = s0.y * __expf(s0.x - nm) + s1.y * __expf(s1.x - nm);
      const u64 pk = ((u64)(unsigned)__float_as_uint(bm[ni]) << 32) |
                     (u64)(unsigned)__float_as_uint(bs[ni]);
      __hip_atomic_store(
          &statmb[((size_t)blockIdx.x * NT + blockIdx.y) * 128 + col], pk,
          __ATOMIC_RELAXED, __HIP_MEMORY_SCOPE_AGENT);
    }
#pragma unroll
    for (int ni = 0; ni < 4; ++ni) {
      const int col = wn * 64 + ni * 16 + lr;
      float M = bm[ni], S = bs[ni];
      for (int i = 0; i < 4; ++i) {
        const int pb = base + i;
        if (pb == (int)blockIdx.x) continue;
        const u64* w = &statmb[((size_t)pb * NT + blockIdx.y) * 128 + col];
        u64 v = pload(w);
        while ((unsigned)(v >> 32) == 0xFFC00000u) v = pload(w);
        const float om = __uint_as_float((unsigned)(v >> 32));
        const float os = __uint_as_float((unsigned)v);
        const float nm = fmaxf(M, om);
        S = S * __expf(M - nm) + os * __expf(om - nm);
        M = nm;
      }
      fstat[col] = make_float2(M, 1.f / S);
    }
  }
  __syncthreads();

  // ---- final write: probabilities, straight from registers ----
#pragma unroll
  for (int ni = 0; ni < 4; ++ni) {
    const int v = n0 + wn * 64 + ni * 16 + lr;
    if (v >= V_) continue;
    const float bias = b_fc[v];
    const float2 fs = fstat[wn * 64 + ni * 16 + lr];
#pragma unroll
    for (int mi = 0; mi < 4; ++mi) {
      const int mrow = m0 + wm * 64 + mi * 16 + lg * 4;
#pragma unroll
      for (int r = 0; r < 4; ++r)
        out[(size_t)(mrow + r) * V_ + v] =
            __expf(acc[mi][ni][r] + bias - fs.x) * fs.y;
    }
  }
}

extern "C" void kernel_launch(void* const* d_in, const int* in_sizes, int n_in,
                              void* d_out, int out_size, void* d_ws,
                              size_t ws_size, hipStream_t stream) {
  const float* x    = (const float*)d_in[0];
  const float* W_ih = (const float*)d_in[1];
  const float* W_hh = (const float*)d_in[2];
  const float* b_ih = (const float*)d_in[3];
  const float* b_hh = (const float*)d_in[4];
  const float* W_fc = (const float*)d_in[5];
  const float* b_fc = (const float*)d_in[6];
  float* out = (float*)d_out;

  // ws layout: xw | hs_b (bf16, own region — k2 writes it while reading xw)
  //            | wfc_hi | wfc_lo | statmb
  //   part (256 KB, scan-only) ALIASES wfc_hi (k2 done before k5_split)
  float* ws = (float*)d_ws;
  float* xw = ws;
  unsigned short* hs_b = (unsigned short*)(xw + (size_t)BS_ * H_);
  unsigned short* wfc_hi = hs_b + (size_t)BS_ * H_;
  unsigned short* wfc_lo = wfc_hi + (size_t)V_ * H_;
  u64* statmb = (u64*)(wfc_lo + (size_t)V_ * H_);  // STAT_WORDS u64
  u64* part = (u64*)wfc_hi;

  k0_init<<<(STAT_WORDS + 255) / 256, 256, 0, stream>>>(part, statmb);
  k1_xw<<<dim3(BS_ / 64, H_ / 64), 256, 0, stream>>>(x, W_ih, b_ih, b_hh, xw);
  k2_scan<<<NBLK, 512, 0, stream>>>(xw, W_hh, hs_b, part);
  k5_split<<<((V_ * H_ / 4) + 255) / 256, 256, 0, stream>>>(W_fc, wfc_hi,
                                                            wfc_lo, V_ * H_ / 4);
  k3_logits<<<dim3(BS_ / 128, NT), 256, 0, stream>>>(hs_b, wfc_hi, wfc_lo,
                                                     b_fc, out, statmb);
}

// Round 21
// 1089.352 us; speedup vs baseline: 1.3889x; 1.0106x over previous
//
#include <hip/hip_runtime.h>
#include <hip/hip_bf16.h>
#include <math.h>

#define B_ 16
#define S_ 512
#define E_ 300
#define H_ 512
#define V_ 10000
#define BS_ (B_ * S_)  // 8192

#define NSL 16           // slices (blocks) per batch, j-split
#define JPB (H_ / NSL)   // 32 output rows per block
#define NBLK (B_ * NSL)  // 256 blocks in the scan
#define NT ((V_ + 127) / 128)  // 79 n-tiles in k3

typedef __attribute__((ext_vector_type(4))) float f32x4;
typedef __attribute__((ext_vector_type(8))) short bf16x8;
typedef unsigned long long u64;

// part region: fast[2][B][H] | safe[2][B][H]  (own ws region now — wfc_hi
// is written BEFORE k2 in the fused prep kernel, so aliasing would corrupt)
#define PART_WORDS (4 * B_ * H_)
// stat mailbox: [mblk=64][nt=79][col=128] u64 (m<<32 | s), NaN-init
#define STAT_WORDS (64 * NT * 128)

// fused prep kernel role ranges
#define K1_BLKS 1024                                   // (BS/64) x (H/64)
#define K5_BLKS ((V_ * H_ / 4) / 256)                  // 5000, exact
#define K0_BLKS ((PART_WORDS + STAT_WORDS) / 256)      // 2656, exact

__device__ __forceinline__ unsigned short bf16_rtn(float f) {
  unsigned u = __float_as_uint(f);
  return (unsigned short)((u + 0x7FFFu + ((u >> 16) & 1u)) >> 16);
}

// ---------------------------------------------------------------------------
// K_PREP: fused k1 (xw GEMM) + k5 (W_fc hi/lo split) + k0 (mailbox init) —
// three independent workloads, role by blockIdx (r21: saves 2 launch gaps
// and overlaps VALU-bound k1 with BW-bound k0/k5). All complete before k2
// (stream order).
// ---------------------------------------------------------------------------
__global__ __launch_bounds__(256) void k_prep(
    const float* __restrict__ x, const float* __restrict__ W_ih,
    const float* __restrict__ b_ih, const float* __restrict__ b_hh,
    float* __restrict__ xw, const float* __restrict__ W_fc,
    unsigned short* __restrict__ wfc_hi, unsigned short* __restrict__ wfc_lo,
    u64* __restrict__ part, u64* __restrict__ statmb) {
  __shared__ float As[64][156];
  __shared__ float Ws[64][156];
  const int id = blockIdx.x;
  const int tid = threadIdx.x;

  if (id < K1_BLKS) {
    // ---- k1: xw = x @ W_ih^T + biases, 64x64 register-blocked (r16) ----
    const int row0 = (id >> 3) * 64;
    const int col0 = (id & 7) * 64;
    const int ty = tid >> 4, tx = tid & 15;
    float acc[4][4];
#pragma unroll
    for (int ii = 0; ii < 4; ++ii)
#pragma unroll
      for (int jj = 0; jj < 4; ++jj) acc[ii][jj] = 0.f;

    for (int idx = tid; idx < 64 * 38; idx += 256) {
      const int r = idx / 38, e4 = idx - r * 38;
      *(float4*)&As[r][e4 * 4] =
          *(const float4*)&x[(size_t)(row0 + r) * E_ + e4 * 4];
      *(float4*)&Ws[r][e4 * 4] =
          *(const float4*)&W_ih[(size_t)(col0 + r) * E_ + e4 * 4];
    }
    __syncthreads();
#pragma unroll 2
    for (int e4 = 0; e4 < 38; ++e4) {
      f32x4 a[4], w[4];
#pragma unroll
      for (int ii = 0; ii < 4; ++ii)
        a[ii] = *(const f32x4*)&As[ty + 16 * ii][e4 * 4];
#pragma unroll
      for (int jj = 0; jj < 4; ++jj)
        w[jj] = *(const f32x4*)&Ws[tx + 16 * jj][e4 * 4];
#pragma unroll
      for (int ii = 0; ii < 4; ++ii)
#pragma unroll
        for (int jj = 0; jj < 4; ++jj) {
          const f32x4 p = a[ii] * w[jj];
          acc[ii][jj] += p.x + p.y + p.z + p.w;
        }
    }
    __syncthreads();

    for (int idx = tid; idx < 64 * 37; idx += 256) {
      const int r = idx / 37, e4 = idx - r * 37;
      *(float4*)&As[r][e4 * 4] =
          *(const float4*)&x[(size_t)(row0 + r) * E_ + 152 + e4 * 4];
      *(float4*)&Ws[r][e4 * 4] =
          *(const float4*)&W_ih[(size_t)(col0 + r) * E_ + 152 + e4 * 4];
    }
    __syncthreads();
#pragma unroll 2
    for (int e4 = 0; e4 < 37; ++e4) {
      f32x4 a[4], w[4];
#pragma unroll
      for (int ii = 0; ii < 4; ++ii)
        a[ii] = *(const f32x4*)&As[ty + 16 * ii][e4 * 4];
#pragma unroll
      for (int jj = 0; jj < 4; ++jj)
        w[jj] = *(const f32x4*)&Ws[tx + 16 * jj][e4 * 4];
#pragma unroll
      for (int ii = 0; ii < 4; ++ii)
#pragma unroll
        for (int jj = 0; jj < 4; ++jj) {
          const f32x4 p = a[ii] * w[jj];
          acc[ii][jj] += p.x + p.y + p.z + p.w;
        }
    }

#pragma unroll
    for (int jj = 0; jj < 4; ++jj) {
      const int h = col0 + tx + 16 * jj;
      const float bb = b_ih[h] + b_hh[h];
#pragma unroll
      for (int ii = 0; ii < 4; ++ii)
        xw[(size_t)(row0 + ty + 16 * ii) * H_ + h] = acc[ii][jj] + bb;
    }
  } else if (id < K1_BLKS + K5_BLKS) {
    // ---- k5: W_fc -> bf16 hi + lo (RTN; lo = f - hi) ----
    const int i = (id - K1_BLKS) * 256 + tid;  // exact: no guard needed
    const float4 f = *(const float4*)&W_fc[(size_t)i * 4];
    unsigned short h[4], l[4];
    const float ff[4] = {f.x, f.y, f.z, f.w};
#pragma unroll
    for (int k = 0; k < 4; ++k) {
      h[k] = bf16_rtn(ff[k]);
      const float fh = __uint_as_float((unsigned)h[k] << 16);
      l[k] = bf16_rtn(ff[k] - fh);
    }
    *(ushort4*)&wfc_hi[(size_t)i * 4] = make_ushort4(h[0], h[1], h[2], h[3]);
    *(ushort4*)&wfc_lo[(size_t)i * 4] = make_ushort4(l[0], l[1], l[2], l[3]);
  } else {
    // ---- k0: invalidate k2 exchange tags + k3 stat mailbox ----
    const int idx = (id - K1_BLKS - K5_BLKS) * 256 + tid;  // exact range
    if (idx < PART_WORDS)
      part[idx] = 0xFFFFFFFF00000000ull;
    else
      statmb[idx - PART_WORDS] = 0xFFC00000FFC00000ull;
  }
}

// sc1 (MALL-coherent) relaxed atomic load — always-correct path
__device__ __forceinline__ u64 pload(const u64* p) {
  return __hip_atomic_load(p, __ATOMIC_RELAXED, __HIP_MEMORY_SCOPE_AGENT);
}
// sc0 (L1-bypass, L2-point) load/store — fast path within one XCD
__device__ __forceinline__ u64 load_sc0(const u64* p) {
  u64 r;
  asm volatile("global_load_dwordx2 %0, %1, off sc0\n\ts_waitcnt vmcnt(0)"
               : "=v"(r) : "v"(p) : "memory");
  return r;
}
__device__ __forceinline__ void store_sc0(u64* p, u64 v) {
  asm volatile("global_store_dwordx2 %0, %1, off sc0" :: "v"(p), "v"(v)
               : "memory");
}

// ---------------------------------------------------------------------------
// K2: scan — r12 protocol VERBATIM + r20 bf16 hs store (banked: 692-708 us
// across r12-r20, FETCH 28.8 MB, WRITE 41 MB, conflicts 0). Failed protocol
// deviations (do not retry): r9 dual-batch, r10 unbounded spin (hang), r11
// deferred sc1, r14 specialized publisher, r17 insurance wave.
// k2 is at its empirical structural floor. DO NOT MODIFY.
// ---------------------------------------------------------------------------
__global__ __launch_bounds__(512) void k2_scan(
    const float* __restrict__ xw, const float* __restrict__ W_hh,
    unsigned short* __restrict__ hs_b, u64* __restrict__ part) {
  const int b = blockIdx.x & 15;  // batch -> XCD b%8 under round-robin
  const int g = blockIdx.x >> 4;  // slice
  const int tid = threadIdx.x;
  const int j = tid >> 4;         // 0..31 row within slice
  const int q = tid & 15;         // k-sixteenth
  const int jg = g * JPB + j;     // global output row

  __shared__ f32x4 Wp[8 * 512];   // 64 KB, instruction-major W
  __shared__ f32x4 hp4[2][128];   // 4 KB, double-buffered h (i4-major)

  {
    const float* wrow = &W_hh[(size_t)jg * H_ + q * 32];
#pragma unroll
    for (int i4 = 0; i4 < 8; ++i4)
      Wp[i4 * 512 + tid] = *(const f32x4*)&wrow[i4 * 4];
  }
  if (tid < 128) hp4[0][tid] = (f32x4)0.f;

  u64* const pf = part + (size_t)b * H_;             // +slot*B*H
  u64* const ps = part + (size_t)(2 * B_ + b) * H_;  // +slot*B*H
  const int kk = ((tid & 63) >> 2) * 32 + (tid >> 6) * 4 + (tid & 3);
  bool fast = true;

  float xwv = xw[(size_t)b * S_ * H_ + jg];  // t = 0
  __syncthreads();

  for (int t = 0; t < S_; ++t) {
    const int cur = t & 1;
    f32x4 a4 = (f32x4)0.f;
#pragma unroll
    for (int i4 = 0; i4 < 8; ++i4) {
      const f32x4 wv = Wp[i4 * 512 + tid];
      const f32x4 hv = hp4[cur][i4 * 16 + q];
      a4 += wv * hv;
    }
    float acc = a4.x + a4.y + a4.z + a4.w;
    acc += __shfl_xor(acc, 1);
    acc += __shfl_xor(acc, 2);
    acc += __shfl_xor(acc, 4);
    acc += __shfl_xor(acc, 8);

    if (q == 0) {
      const float hn = tanhf(xwv + acc);
      const u64 pk =
          ((u64)(unsigned)t << 32) | (u64)(unsigned)__float_as_uint(hn);
      store_sc0(&pf[(size_t)cur * (B_ * H_) + jg], pk);
      __hip_atomic_store(&ps[(size_t)cur * (B_ * H_) + jg], pk,
                         __ATOMIC_RELAXED, __HIP_MEMORY_SCOPE_AGENT);
      hs_b[((size_t)b * S_ + t) * H_ + jg] = bf16_rtn(hn);
    }
    const int tn = (t + 1 < S_) ? t + 1 : t;
    const float xw_next = xw[((size_t)b * S_ + tn) * H_ + jg];

    if (t + 1 < S_) {
      u64 v = 0;
      bool got = false;
      const u64* fw = &pf[(size_t)cur * (B_ * H_) + kk];
      if (fast) {
        for (int it = 0; it < 64; ++it) {
          v = load_sc0(fw);
          if ((unsigned)(v >> 32) == (unsigned)t) { got = true; break; }
        }
        if (!got) fast = false;  // sticky downgrade (cross-XCD placement)
      }
      if (!got) {
        const u64* sw = &ps[(size_t)cur * (B_ * H_) + kk];
        v = pload(sw);
        while ((unsigned)(v >> 32) != (unsigned)t) v = pload(sw);
      }
      ((float*)&hp4[cur ^ 1][0])[tid] = __uint_as_float((unsigned)v);
    }
    xwv = xw_next;
    __syncthreads();
  }
}

// ---------------------------------------------------------------------------
// K3: FULLY FUSED logits + softmax (banked r19/r20). 2-product bf16 MFMA,
// tagged-u64 cross-block stat exchange, final probabilities from registers.
// ---------------------------------------------------------------------------
__global__ __launch_bounds__(256) void k3_logits(
    const unsigned short* __restrict__ Abg, const unsigned short* __restrict__ Bhg,
    const unsigned short* __restrict__ Blg, const float* __restrict__ b_fc,
    float* __restrict__ out, u64* __restrict__ statmb) {
  __shared__ unsigned short Ab[2][128 * 32];
  __shared__ unsigned short Bh[2][128 * 32];
  __shared__ unsigned short Bl[2][128 * 32];
  __shared__ float2 sstat[2][2][4][16];  // [wm][wn][ni][lr]
  __shared__ float2 fstat[128];          // final (M, 1/S) per column
  const int m0 = blockIdx.x * 128;
  const int n0 = blockIdx.y * 128;
  const int tid = threadIdx.x;
  const int lane = tid & 63;
  const int wave = tid >> 6;
  const int wm = wave >> 1, wn = wave & 1;
  const int lr = lane & 15;
  const int lg = lane >> 4;
  const int cxr = (lg ^ (lr & 3)) * 8;  // swizzled k-chunk (shorts)
  const int lrow = lane >> 2;
  const int lchunk = (lane & 3) ^ (lrow & 3);

  const unsigned short* src[6];
  unsigned short* d0[6];
  unsigned short* d1[6];
#pragma unroll
  for (int t = 0; t < 6; ++t) {
    const int id = wave * 6 + t;
    const int arr = id >> 3;  // 0:Ab 1:Bh 2:Bl (wave-uniform)
    const int c16 = id & 7;
    const int r = c16 * 16 + lrow;
    const int grow = (arr == 0) ? (m0 + r) : min(n0 + r, V_ - 1);
    const unsigned short* g = (arr == 0) ? Abg : (arr == 1) ? Bhg : Blg;
    src[t] = g + (size_t)grow * H_ + lchunk * 8;
    unsigned short* l0 = (arr == 0) ? Ab[0] : (arr == 1) ? Bh[0] : Bl[0];
    unsigned short* l1 = (arr == 0) ? Ab[1] : (arr == 1) ? Bh[1] : Bl[1];
    d0[t] = l0 + c16 * 512;
    d1[t] = l1 + c16 * 512;
  }

  f32x4 acc[4][4];
#pragma unroll
  for (int mi = 0; mi < 4; ++mi)
#pragma unroll
    for (int ni = 0; ni < 4; ++ni) acc[mi][ni] = (f32x4)0.0f;

  auto STAGE0 = [&](int k0) {
#pragma unroll
    for (int t = 0; t < 6; ++t)
      __builtin_amdgcn_global_load_lds(
          (const __attribute__((address_space(1))) void*)(src[t] + k0),
          (__attribute__((address_space(3))) void*)d0[t], 16, 0, 0);
  };
  auto STAGE1 = [&](int k0) {
#pragma unroll
    for (int t = 0; t < 6; ++t)
      __builtin_amdgcn_global_load_lds(
          (const __attribute__((address_space(1))) void*)(src[t] + k0),
          (__attribute__((address_space(3))) void*)d1[t], 16, 0, 0);
  };
  auto COMPUTE = [&](int buf) {
    bf16x8 ab[4], bh[4], bl[4];
#pragma unroll
    for (int i = 0; i < 4; ++i) {
      ab[i] = *(const bf16x8*)&Ab[buf][(wm * 64 + i * 16 + lr) * 32 + cxr];
      bh[i] = *(const bf16x8*)&Bh[buf][(wn * 64 + i * 16 + lr) * 32 + cxr];
      bl[i] = *(const bf16x8*)&Bl[buf][(wn * 64 + i * 16 + lr) * 32 + cxr];
    }
#pragma unroll
    for (int mi = 0; mi < 4; ++mi)
#pragma unroll
      for (int ni = 0; ni < 4; ++ni) {
        acc[mi][ni] = __builtin_amdgcn_mfma_f32_16x16x32_bf16(
            ab[mi], bh[ni], acc[mi][ni], 0, 0, 0);
        acc[mi][ni] = __builtin_amdgcn_mfma_f32_16x16x32_bf16(
            ab[mi], bl[ni], acc[mi][ni], 0, 0, 0);
      }
  };

  STAGE0(0);
  __syncthreads();
  for (int kt = 0; kt < 16; kt += 2) {
    STAGE1((kt + 1) * 32);
    COMPUTE(0);
    __syncthreads();
    if (kt + 2 < 16) STAGE0((kt + 2) * 32);
    COMPUTE(1);
    __syncthreads();
  }

  // ---- per-block softmax partials ----
  float pm[4], psum[4];
#pragma unroll
  for (int ni = 0; ni < 4; ++ni) {
    const int v = n0 + wn * 64 + ni * 16 + lr;
    float m = -3.4e38f, s = 0.f;
    if (v < V_) {
      const float bias = b_fc[v];
#pragma unroll
      for (int mi = 0; mi < 4; ++mi)
#pragma unroll
        for (int r = 0; r < 4; ++r)
          m = fmaxf(m, acc[mi][ni][r] + bias);
#pragma unroll
      for (int mi = 0; mi < 4; ++mi)
#pragma unroll
        for (int r = 0; r < 4; ++r)
          s += __expf(acc[mi][ni][r] + bias - m);
    }
#pragma unroll
    for (int d = 16; d <= 32; d <<= 1) {
      const float om = __shfl_xor(m, d);
      const float os = __shfl_xor(s, d);
      const float nm = fmaxf(m, om);
      s = s * __expf(m - nm) + os * __expf(om - nm);
      m = nm;
    }
    pm[ni] = m;
    psum[ni] = s;
  }
  __syncthreads();
  if (lg == 0) {
#pragma unroll
    for (int ni = 0; ni < 4; ++ni)
      sstat[wm][wn][ni][lr] = make_float2(pm[ni], psum[ni]);
  }
  __syncthreads();

  // ---- cross-block exchange + finalize (waves 0-1, lanes lg==0) ----
  if (wave < 2 && lg == 0) {
    const int base = (int)(blockIdx.x & ~3u);
    float bm[4], bs[4];
#pragma unroll
    for (int ni = 0; ni < 4; ++ni) {
      const int col = wn * 64 + ni * 16 + lr;
      const float2 s0 = sstat[0][wn][ni][lr];
      const float2 s1 = sstat[1][wn][ni][lr];
      const float nm = fmaxf(s0.x, s1.x);
      bm[ni] = nm;
      bs[ni] = s0.y * __expf(s0.x - nm) + s1.y * __expf(s1.x - nm);
      const u64 pk = ((u64)(unsigned)__float_as_uint(bm[ni]) << 32) |
                     (u64)(unsigned)__float_as_uint(bs[ni]);
      __hip_atomic_store(
          &statmb[((size_t)blockIdx.x * NT + blockIdx.y) * 128 + col], pk,
          __ATOMIC_RELAXED, __HIP_MEMORY_SCOPE_AGENT);
    }
#pragma unroll
    for (int ni = 0; ni < 4; ++ni) {
      const int col = wn * 64 + ni * 16 + lr;
      float M = bm[ni], S = bs[ni];
      for (int i = 0; i < 4; ++i) {
        const int pb = base + i;
        if (pb == (int)blockIdx.x) continue;
        const u64* w = &statmb[((size_t)pb * NT + blockIdx.y) * 128 + col];
        u64 v = pload(w);
        while ((unsigned)(v >> 32) == 0xFFC00000u) v = pload(w);
        const float om = __uint_as_float((unsigned)(v >> 32));
        const float os = __uint_as_float((unsigned)v);
        const float nm = fmaxf(M, om);
        S = S * __expf(M - nm) + os * __expf(om - nm);
        M = nm;
      }
      fstat[col] = make_float2(M, 1.f / S);
    }
  }
  __syncthreads();

  // ---- final write: probabilities, straight from registers ----
#pragma unroll
  for (int ni = 0; ni < 4; ++ni) {
    const int v = n0 + wn * 64 + ni * 16 + lr;
    if (v >= V_) continue;
    const float bias = b_fc[v];
    const float2 fs = fstat[wn * 64 + ni * 16 + lr];
#pragma unroll
    for (int mi = 0; mi < 4; ++mi) {
      const int mrow = m0 + wm * 64 + mi * 16 + lg * 4;
#pragma unroll
      for (int r = 0; r < 4; ++r)
        out[(size_t)(mrow + r) * V_ + v] =
            __expf(acc[mi][ni][r] + bias - fs.x) * fs.y;
    }
  }
}

extern "C" void kernel_launch(void* const* d_in, const int* in_sizes, int n_in,
                              void* d_out, int out_size, void* d_ws,
                              size_t ws_size, hipStream_t stream) {
  const float* x    = (const float*)d_in[0];
  const float* W_ih = (const float*)d_in[1];
  const float* W_hh = (const float*)d_in[2];
  const float* b_ih = (const float*)d_in[3];
  const float* b_hh = (const float*)d_in[4];
  const float* W_fc = (const float*)d_in[5];
  const float* b_fc = (const float*)d_in[6];
  float* out = (float*)d_out;

  // ws layout: xw | hs_b | wfc_hi | wfc_lo | statmb | part  (~70 MB)
  //   part no longer aliases wfc_hi: prep writes wfc BEFORE k2 runs.
  float* ws = (float*)d_ws;
  float* xw = ws;
  unsigned short* hs_b = (unsigned short*)(xw + (size_t)BS_ * H_);
  unsigned short* wfc_hi = hs_b + (size_t)BS_ * H_;
  unsigned short* wfc_lo = wfc_hi + (size_t)V_ * H_;
  u64* statmb = (u64*)(wfc_lo + (size_t)V_ * H_);
  u64* part = statmb + (size_t)STAT_WORDS;

  k_prep<<<K1_BLKS + K5_BLKS + K0_BLKS, 256, 0, stream>>>(
      x, W_ih, b_ih, b_hh, xw, W_fc, wfc_hi, wfc_lo, part, statmb);
  k2_scan<<<NBLK, 512, 0, stream>>>(xw, W_hh, hs_b, part);
  k3_logits<<<dim3(BS_ / 128, NT), 256, 0, stream>>>(hs_b, wfc_hi, wfc_lo,
                                                     b_fc, out, statmb);
}